// Round 1
// baseline (224.852 us; speedup 1.0000x reference)
//
#include <hip/hip_runtime.h>

// ParallelHybridScan: chunked 3-phase linear scan, fp32 throughout (exact reassociation).
// B=4 L=2048 H=16 D=64 N=64. Chunks of T=64 -> C=32. BH=64 independent sequences.

#define B_SZ 4
#define L_SZ 2048
#define H_SZ 16
#define D_SZ 64
#define N_SZ 64
#define T_CH 64
#define C_CH (L_SZ / T_CH)   // 32
#define BH (B_SZ * H_SZ)     // 64
#define STRIDE_T (H_SZ * D_SZ)  // 1024 floats per timestep

// --- Bs precompute: Bs[b*L+t] = mean over N of B_vec ---
__global__ __launch_bounds__(256) void bs_kernel(const float* __restrict__ Bvec,
                                                 float* __restrict__ Bs) {
    int wid = (blockIdx.x * 256 + threadIdx.x) >> 6;   // one wave per row
    int lane = threadIdx.x & 63;
    if (wid >= B_SZ * L_SZ) return;
    float s = Bvec[wid * N_SZ + lane];
    #pragma unroll
    for (int m = 32; m >= 1; m >>= 1) s += __shfl_xor(s, m, 64);
    if (lane == 0) Bs[wid] = s * (1.0f / 64.0f);
}

// --- Phase 1: per-chunk from zero state. P[k]=prod decay, Q[k,v]=chunk accum ---
__global__ __launch_bounds__(64) void phase1(const float* __restrict__ kq,
                                             const float* __restrict__ vq,
                                             const float* __restrict__ dq,
                                             const float* __restrict__ Bs,
                                             const float* __restrict__ bd,
                                             float* __restrict__ P,
                                             float* __restrict__ Q) {
    int c = blockIdx.x, bh = blockIdx.y;
    int b = bh >> 4, h = bh & 15;
    int lane = threadIdx.x;
    alignas(16) __shared__ float2 sh[2][D_SZ];

    float S[D_SZ];
    #pragma unroll
    for (int i = 0; i < D_SZ; i++) S[i] = 0.f;

    float bdl = bd[h * D_SZ + lane];
    float Pl = 1.f;
    int t0 = c * T_CH;
    int base = ((b * L_SZ + t0) * H_SZ + h) * D_SZ + lane;

    for (int tt = 0; tt < T_CH; tt++) {
        int off = base + tt * STRIDE_T;
        float kt = kq[off];
        float vt = vq[off];
        float dtt = dq[off];
        float bsv = Bs[b * L_SZ + t0 + tt];
        float d = __expf(-bdl * dtt);
        sh[tt & 1][lane] = make_float2(d, kt);
        Pl *= d;
        float bv = bsv * vt;
        __syncthreads();
        const float4* sh4 = (const float4*)sh[tt & 1];
        #pragma unroll
        for (int kk = 0; kk < 32; kk++) {
            float4 pq = sh4[kk];
            S[2 * kk]     = pq.x * S[2 * kk]     + bv * pq.y;
            S[2 * kk + 1] = pq.z * S[2 * kk + 1] + bv * pq.w;
        }
    }

    P[(bh * C_CH + c) * D_SZ + lane] = Pl;
    int qb = ((bh * C_CH + c) * D_SZ) * D_SZ + lane;
    #pragma unroll
    for (int kk = 0; kk < D_SZ; kk++) Q[qb + kk * D_SZ] = S[kk];
}

// --- Phase 2: sequential combine over chunks. Overwrites Q[c] with chunk-start state.
//     Writes final state to out2 ([B,H,D,D]). 64 blocks x 4 waves (k-split). ---
__global__ __launch_bounds__(256) void phase2(const float* __restrict__ P,
                                              float* __restrict__ Q,
                                              float* __restrict__ out2) {
    int bh = blockIdx.x;
    int w = threadIdx.x >> 6, lane = threadIdx.x & 63;
    float S[16];
    #pragma unroll
    for (int i = 0; i < 16; i++) S[i] = 0.f;

    for (int c = 0; c < C_CH; c++) {
        int pb = (bh * C_CH + c) * D_SZ + w * 16;
        int qb = ((bh * C_CH + c) * D_SZ + w * 16) * D_SZ + lane;
        #pragma unroll
        for (int i = 0; i < 16; i++) {
            float p = P[pb + i];
            float q = Q[qb + i * D_SZ];
            Q[qb + i * D_SZ] = S[i];          // chunk-start state for phase 3
            S[i] = p * S[i] + q;
        }
    }
    int ob = (bh * D_SZ + w * 16) * D_SZ + lane;
    #pragma unroll
    for (int i = 0; i < 16; i++) out2[ob + i * D_SZ] = S[i];
}

// --- Phase 3: replay chunk from start state, emit outputs ---
__global__ __launch_bounds__(64) void phase3(const float* __restrict__ kq,
                                             const float* __restrict__ vq,
                                             const float* __restrict__ dq,
                                             const float* __restrict__ rq,
                                             const float* __restrict__ gq,
                                             const float* __restrict__ Bs,
                                             const float* __restrict__ bd,
                                             const float* __restrict__ tf,
                                             const float* __restrict__ Sstart,
                                             float* __restrict__ out) {
    int c = blockIdx.x, bh = blockIdx.y;
    int b = bh >> 4, h = bh & 15;
    int lane = threadIdx.x;
    alignas(16) __shared__ float2 sh[2][D_SZ];

    float S[D_SZ];
    int sb = ((bh * C_CH + c) * D_SZ) * D_SZ + lane;
    #pragma unroll
    for (int i = 0; i < D_SZ; i++) S[i] = Sstart[sb + i * D_SZ];

    float bdl = bd[h * D_SZ + lane];
    float tfl = tf[h * D_SZ + lane];
    int t0 = c * T_CH;
    int base = ((b * L_SZ + t0) * H_SZ + h) * D_SZ + lane;

    for (int tt = 0; tt < T_CH; tt++) {
        int off = base + tt * STRIDE_T;
        float kt = kq[off];
        float vt = vq[off];
        float dtt = dq[off];
        float rt = rq[off];
        float gt = gq[off];
        float bsv = Bs[b * L_SZ + t0 + tt];
        float d = __expf(-bdl * dtt);
        sh[tt & 1][lane] = make_float2(d, kt);
        float bv = bsv * vt;
        __syncthreads();
        const float4* sh4 = (const float4*)sh[tt & 1];
        float acc0 = 0.f, acc1 = 0.f, acc2 = 0.f, acc3 = 0.f;
        #pragma unroll
        for (int kk = 0; kk < 32; kk++) {
            float4 pq = sh4[kk];
            float sA = pq.x * S[2 * kk]     + bv * pq.y;
            float sB = pq.z * S[2 * kk + 1] + bv * pq.w;
            S[2 * kk]     = sA;
            S[2 * kk + 1] = sB;
            if (kk & 1) { acc2 += sA * pq.y; acc3 += sB * pq.w; }
            else        { acc0 += sA * pq.y; acc1 += sB * pq.w; }
        }
        float wkv = (acc0 + acc1) + (acc2 + acc3);
        wkv += tfl * kt * vt;
        out[off] = rt * wkv * gt;
    }
}

extern "C" void kernel_launch(void* const* d_in, const int* in_sizes, int n_in,
                              void* d_out, int out_size, void* d_ws, size_t ws_size,
                              hipStream_t stream) {
    const float* k    = (const float*)d_in[0];
    const float* v    = (const float*)d_in[1];
    const float* dt   = (const float*)d_in[2];
    const float* Bvec = (const float*)d_in[3];
    // d_in[4] = C_vec (unused by reference)
    const float* r    = (const float*)d_in[5];
    const float* g    = (const float*)d_in[6];
    const float* bd   = (const float*)d_in[7];
    const float* tf   = (const float*)d_in[8];

    float* out  = (float*)d_out;                                  // [B,L,H,D]
    float* out2 = out + (size_t)B_SZ * L_SZ * H_SZ * D_SZ;        // [B,H,D,D]

    float* Bs = (float*)d_ws;                       // B*L floats          (32 KB)
    float* P  = Bs + B_SZ * L_SZ;                   // BH*C*D floats       (512 KB)
    float* Q  = P + BH * C_CH * D_SZ;               // BH*C*D*D floats     (33.5 MB)

    bs_kernel<<<dim3(B_SZ * L_SZ / 4), 256, 0, stream>>>(Bvec, Bs);
    phase1<<<dim3(C_CH, BH), 64, 0, stream>>>(k, v, dt, Bs, bd, P, Q);
    phase2<<<dim3(BH), 256, 0, stream>>>(P, Q, out2);
    phase3<<<dim3(C_CH, BH), 64, 0, stream>>>(k, v, dt, r, g, Bs, bd, tf, Q, out);
}

// Round 2
// 204.938 us; speedup vs baseline: 1.0972x; 1.0972x over previous
//
#include <hip/hip_runtime.h>

// ParallelHybridScan: chunked linear scan reformulated as per-chunk matmuls.
// B=4 L=2048 H=16 D=64. Chunk T=64 -> C=32. BH=64 sequences.
// q~[t,k]=k*exp(-bd*cs[t,k]); k~[t,k]=Bs_t*k*exp(+bd*cs[t,k]); a_T=exp(-bd*cs[63,k])
// Phase1: Q_c = diag(a_T) * (K~^T V); P_c = a_T           (per chunk, from zero state)
// Phase2: sequential combine S_{c+1} = P_c*S_c + Q_c      (overwrites Q with start states)
// Phase3: O = (q~ k~^T . causal) V + q~ S0; out = r*(O + tf*k*v)*g

#define B_SZ 4
#define L_SZ 2048
#define H_SZ 16
#define D_SZ 64
#define N_SZ 64
#define T_CH 64
#define C_CH (L_SZ / T_CH)   // 32
#define BH (B_SZ * H_SZ)     // 64
#define STRIDE_T (H_SZ * D_SZ)

// XOR swizzle for tiles read as [16-distinct-rows][same col-range] (k~ tile).
// s(row) uses row bits >=2 because tau = 4*(tid&15)+j across lanes.
__device__ __forceinline__ int swz(int row, int col) {
    return col ^ (((row >> 2) & 7) << 2);
}

__global__ __launch_bounds__(256) void bs_kernel(const float* __restrict__ Bvec,
                                                 float* __restrict__ Bs) {
    int wid = (blockIdx.x * 256 + threadIdx.x) >> 6;
    int lane = threadIdx.x & 63;
    if (wid >= B_SZ * L_SZ) return;
    float s = Bvec[wid * N_SZ + lane];
    #pragma unroll
    for (int m = 32; m >= 1; m >>= 1) s += __shfl_xor(s, m, 64);
    if (lane == 0) Bs[wid] = s * (1.0f / 64.0f);
}

__global__ __launch_bounds__(256) void phase1_mm(
    const float* __restrict__ kq, const float* __restrict__ vq,
    const float* __restrict__ dq, const float* __restrict__ Bs,
    const float* __restrict__ bd, float* __restrict__ P, float* __restrict__ Q)
{
    int c = blockIdx.x, bh = blockIdx.y;
    int b = bh >> 4, h = bh & 15;
    int tid = threadIdx.x;
    alignas(16) __shared__ float tA[T_CH][D_SZ];  // dt -> csum
    alignas(16) __shared__ float tB[T_CH][D_SZ];  // k -> ktil
    alignas(16) __shared__ float tC[T_CH][D_SZ];  // v
    __shared__ float part[4][D_SZ];

    int t0 = c * T_CH;
    int q4 = (tid & 15) * 4;
    int tr = tid >> 4;
    size_t base = ((size_t)(b * L_SZ + t0) * H_SZ + h) * D_SZ;

    #pragma unroll
    for (int i = 0; i < 4; i++) {
        int t = tr + 16 * i;
        size_t off = base + (size_t)t * STRIDE_T + q4;
        *(float4*)&tA[t][q4] = *(const float4*)&dq[off];
        *(float4*)&tB[t][q4] = *(const float4*)&kq[off];
        *(float4*)&tC[t][q4] = *(const float4*)&vq[off];
    }
    __syncthreads();

    // inclusive cumsum along t, in place in tA (64 independent columns)
    {
        int k = tid & 63, qq = tid >> 6;
        float p = 0.f;
        #pragma unroll
        for (int t = 0; t < 16; t++) p += tA[qq * 16 + t][k];
        part[qq][k] = p;
        __syncthreads();
        float o = 0.f;
        #pragma unroll
        for (int j = 0; j < 3; j++) if (j < qq) o += part[j][k];
        #pragma unroll
        for (int t = 0; t < 16; t++) {
            o += tA[qq * 16 + t][k];
            tA[qq * 16 + t][k] = o;
        }
    }
    __syncthreads();

    // ktil in place over tB
    float4 bd4 = *(const float4*)&bd[h * D_SZ + q4];
    #pragma unroll
    for (int i = 0; i < 4; i++) {
        int t = tr + 16 * i;
        float bs = Bs[b * L_SZ + t0 + t];
        float4 cs = *(float4*)&tA[t][q4];
        float4 kk = *(float4*)&tB[t][q4];
        float4 kt;
        kt.x = bs * kk.x * __expf(bd4.x * cs.x);
        kt.y = bs * kk.y * __expf(bd4.y * cs.y);
        kt.z = bs * kk.z * __expf(bd4.z * cs.z);
        kt.w = bs * kk.w * __expf(bd4.w * cs.w);
        *(float4*)&tB[t][q4] = kt;
    }
    __syncthreads();

    // out[k][v] = aT[k] * sum_tau ktil[tau][k] * v[tau][v]
    float acc[4][4] = {};
    #pragma unroll 4
    for (int tau = 0; tau < T_CH; tau++) {
        float4 vv = *(const float4*)&tC[tau][q4];
        float kt0 = tB[tau][tr];
        float kt1 = tB[tau][tr + 16];
        float kt2 = tB[tau][tr + 32];
        float kt3 = tB[tau][tr + 48];
        acc[0][0] = fmaf(kt0, vv.x, acc[0][0]); acc[0][1] = fmaf(kt0, vv.y, acc[0][1]);
        acc[0][2] = fmaf(kt0, vv.z, acc[0][2]); acc[0][3] = fmaf(kt0, vv.w, acc[0][3]);
        acc[1][0] = fmaf(kt1, vv.x, acc[1][0]); acc[1][1] = fmaf(kt1, vv.y, acc[1][1]);
        acc[1][2] = fmaf(kt1, vv.z, acc[1][2]); acc[1][3] = fmaf(kt1, vv.w, acc[1][3]);
        acc[2][0] = fmaf(kt2, vv.x, acc[2][0]); acc[2][1] = fmaf(kt2, vv.y, acc[2][1]);
        acc[2][2] = fmaf(kt2, vv.z, acc[2][2]); acc[2][3] = fmaf(kt2, vv.w, acc[2][3]);
        acc[3][0] = fmaf(kt3, vv.x, acc[3][0]); acc[3][1] = fmaf(kt3, vv.y, acc[3][1]);
        acc[3][2] = fmaf(kt3, vv.z, acc[3][2]); acc[3][3] = fmaf(kt3, vv.w, acc[3][3]);
    }

    int kbase = h * D_SZ;
    #pragma unroll
    for (int i = 0; i < 4; i++) {
        int kr = tr + 16 * i;
        float aT = __expf(-bd[kbase + kr] * tA[63][kr]);
        float4 o;
        o.x = aT * acc[i][0]; o.y = aT * acc[i][1];
        o.z = aT * acc[i][2]; o.w = aT * acc[i][3];
        *(float4*)&Q[((size_t)(bh * C_CH + c) * D_SZ + kr) * D_SZ + q4] = o;
    }
    if (tid < D_SZ)
        P[(size_t)(bh * C_CH + c) * D_SZ + tid] = __expf(-bd[kbase + tid] * tA[63][tid]);
}

// Sequential combine over chunks; (bh, kq) blocks, 16 k-rows each.
__global__ __launch_bounds__(64) void phase2(const float* __restrict__ P,
                                             float* __restrict__ Q,
                                             float* __restrict__ out2) {
    int bh = blockIdx.x, kq = blockIdx.y;
    int lane = threadIdx.x;
    float S[16];
    #pragma unroll
    for (int i = 0; i < 16; i++) S[i] = 0.f;

    for (int c = 0; c < C_CH; c++) {
        size_t pb = (size_t)(bh * C_CH + c) * D_SZ + kq * 16;
        size_t qb = ((size_t)(bh * C_CH + c) * D_SZ + kq * 16) * D_SZ + lane;
        #pragma unroll
        for (int i = 0; i < 16; i++) {
            float p = P[pb + i];
            float q = Q[qb + i * D_SZ];
            Q[qb + i * D_SZ] = S[i];
            S[i] = fmaf(p, S[i], q);
        }
    }
    size_t ob = ((size_t)bh * D_SZ + kq * 16) * D_SZ + lane;
    #pragma unroll
    for (int i = 0; i < 16; i++) out2[ob + i * D_SZ] = S[i];
}

__global__ __launch_bounds__(256) void phase3_mm(
    const float* __restrict__ kq, const float* __restrict__ vq,
    const float* __restrict__ dq, const float* __restrict__ rq,
    const float* __restrict__ gq, const float* __restrict__ Bs,
    const float* __restrict__ bd, const float* __restrict__ tf,
    const float* __restrict__ Sstart, float* __restrict__ out)
{
    int c = blockIdx.x, bh = blockIdx.y;
    int b = bh >> 4, h = bh & 15;
    int tid = threadIdx.x;
    alignas(16) __shared__ float tA[T_CH][D_SZ];  // dt -> csum -> G(masked)
    alignas(16) __shared__ float tB[T_CH][D_SZ];  // k
    alignas(16) __shared__ float tC[T_CH][D_SZ];  // v
    alignas(16) __shared__ float tD[T_CH][D_SZ];  // (csum partials) -> qtil
    alignas(16) __shared__ float tE[T_CH][D_SZ];  // S0 (swizzled) -> ktil (swizzled)

    int t0 = c * T_CH;
    int v4 = (tid & 15) * 4;
    int tr = tid >> 4;
    size_t base = ((size_t)(b * L_SZ + t0) * H_SZ + h) * D_SZ;
    size_t sb = (size_t)(bh * C_CH + c) * D_SZ * D_SZ;

    #pragma unroll
    for (int i = 0; i < 4; i++) {
        int t = tr + 16 * i;
        size_t off = base + (size_t)t * STRIDE_T + v4;
        *(float4*)&tA[t][v4] = *(const float4*)&dq[off];
        *(float4*)&tB[t][v4] = *(const float4*)&kq[off];
        *(float4*)&tC[t][v4] = *(const float4*)&vq[off];
        *(float4*)&tE[t][swz(t, v4)] = *(const float4*)&Sstart[sb + (size_t)t * D_SZ + v4];
    }
    __syncthreads();

    // inclusive cumsum along t in tA; partials staged in tD rows 0..3
    {
        int k = tid & 63, qq = tid >> 6;
        float p = 0.f;
        #pragma unroll
        for (int t = 0; t < 16; t++) p += tA[qq * 16 + t][k];
        tD[qq][k] = p;
        __syncthreads();
        float o = 0.f;
        #pragma unroll
        for (int j = 0; j < 3; j++) if (j < qq) o += tD[j][k];
        #pragma unroll
        for (int t = 0; t < 16; t++) {
            o += tA[qq * 16 + t][k];
            tA[qq * 16 + t][k] = o;
        }
    }
    __syncthreads();

    // qtil -> tD
    float4 bd4 = *(const float4*)&bd[h * D_SZ + v4];
    #pragma unroll
    for (int i = 0; i < 4; i++) {
        int t = tr + 16 * i;
        float4 cs = *(float4*)&tA[t][v4];
        float4 kk = *(float4*)&tB[t][v4];
        float4 qt;
        qt.x = kk.x * __expf(-bd4.x * cs.x);
        qt.y = kk.y * __expf(-bd4.y * cs.y);
        qt.z = kk.z * __expf(-bd4.z * cs.z);
        qt.w = kk.w * __expf(-bd4.w * cs.w);
        *(float4*)&tD[t][v4] = qt;
    }
    __syncthreads();

    // matmul1: acc[t][v] += qtil[t][k] * S0[k][v]
    float acc[4][4] = {};
    for (int k4 = 0; k4 < D_SZ; k4 += 4) {
        float4 qa[4];
        #pragma unroll
        for (int i = 0; i < 4; i++) qa[i] = *(const float4*)&tD[tr + 16 * i][k4];
        #pragma unroll
        for (int m = 0; m < 4; m++) {
            float4 s4 = *(const float4*)&tE[k4 + m][swz(k4 + m, v4)];
            #pragma unroll
            for (int i = 0; i < 4; i++) {
                float qv = (&qa[i].x)[m];
                acc[i][0] = fmaf(qv, s4.x, acc[i][0]);
                acc[i][1] = fmaf(qv, s4.y, acc[i][1]);
                acc[i][2] = fmaf(qv, s4.z, acc[i][2]);
                acc[i][3] = fmaf(qv, s4.w, acc[i][3]);
            }
        }
    }
    __syncthreads();   // done reading tE (S0)

    // ktil -> tE (swizzled)
    #pragma unroll
    for (int i = 0; i < 4; i++) {
        int t = tr + 16 * i;
        float bs = Bs[b * L_SZ + t0 + t];
        float4 cs = *(float4*)&tA[t][v4];
        float4 kk = *(float4*)&tB[t][v4];
        float4 kt;
        kt.x = bs * kk.x * __expf(bd4.x * cs.x);
        kt.y = bs * kk.y * __expf(bd4.y * cs.y);
        kt.z = bs * kk.z * __expf(bd4.z * cs.z);
        kt.w = bs * kk.w * __expf(bd4.w * cs.w);
        *(float4*)&tE[t][swz(t, v4)] = kt;
    }
    __syncthreads();   // tE ready; tA (csum) no longer needed after this point

    // G[t][tau] = sum_k qtil[t][k]*ktil[tau][k]  (t rows = tr+16i, tau quad = v4+j)
    float g[4][4] = {};
    for (int k4 = 0; k4 < D_SZ; k4 += 4) {
        float4 qa[4], kb[4];
        #pragma unroll
        for (int i = 0; i < 4; i++) qa[i] = *(const float4*)&tD[tr + 16 * i][k4];
        #pragma unroll
        for (int j = 0; j < 4; j++) kb[j] = *(const float4*)&tE[v4 + j][swz(v4 + j, k4)];
        #pragma unroll
        for (int i = 0; i < 4; i++) {
            #pragma unroll
            for (int j = 0; j < 4; j++) {
                g[i][j] = fmaf(qa[i].x, kb[j].x, g[i][j]);
                g[i][j] = fmaf(qa[i].y, kb[j].y, g[i][j]);
                g[i][j] = fmaf(qa[i].z, kb[j].z, g[i][j]);
                g[i][j] = fmaf(qa[i].w, kb[j].w, g[i][j]);
            }
        }
    }
    // masked G -> tA
    #pragma unroll
    for (int i = 0; i < 4; i++) {
        int t = tr + 16 * i;
        float4 gm;
        gm.x = (v4 + 0 <= t) ? g[i][0] : 0.f;
        gm.y = (v4 + 1 <= t) ? g[i][1] : 0.f;
        gm.z = (v4 + 2 <= t) ? g[i][2] : 0.f;
        gm.w = (v4 + 3 <= t) ? g[i][3] : 0.f;
        *(float4*)&tA[t][v4] = gm;
    }
    __syncthreads();

    // matmul2: acc[t][v] += G[t][tau] * v[tau][v]
    for (int p4 = 0; p4 < T_CH; p4 += 4) {
        float4 ga[4];
        #pragma unroll
        for (int i = 0; i < 4; i++) ga[i] = *(const float4*)&tA[tr + 16 * i][p4];
        #pragma unroll
        for (int m = 0; m < 4; m++) {
            float4 vv = *(const float4*)&tC[p4 + m][v4];
            #pragma unroll
            for (int i = 0; i < 4; i++) {
                float gv = (&ga[i].x)[m];
                acc[i][0] = fmaf(gv, vv.x, acc[i][0]);
                acc[i][1] = fmaf(gv, vv.y, acc[i][1]);
                acc[i][2] = fmaf(gv, vv.z, acc[i][2]);
                acc[i][3] = fmaf(gv, vv.w, acc[i][3]);
            }
        }
    }

    // epilogue: out = r * (acc + tf*k*v) * g
    float4 tf4 = *(const float4*)&tf[h * D_SZ + v4];
    #pragma unroll
    for (int i = 0; i < 4; i++) {
        int t = tr + 16 * i;
        size_t off = base + (size_t)t * STRIDE_T + v4;
        float4 r4 = *(const float4*)&rq[off];
        float4 g4 = *(const float4*)&gq[off];
        float4 kk = *(float4*)&tB[t][v4];
        float4 vv = *(const float4*)&tC[t][v4];
        float4 o;
        o.x = r4.x * fmaf(tf4.x, kk.x * vv.x, acc[i][0]) * g4.x;
        o.y = r4.y * fmaf(tf4.y, kk.y * vv.y, acc[i][1]) * g4.y;
        o.z = r4.z * fmaf(tf4.z, kk.z * vv.z, acc[i][2]) * g4.z;
        o.w = r4.w * fmaf(tf4.w, kk.w * vv.w, acc[i][3]) * g4.w;
        *(float4*)&out[off] = o;
    }
}

extern "C" void kernel_launch(void* const* d_in, const int* in_sizes, int n_in,
                              void* d_out, int out_size, void* d_ws, size_t ws_size,
                              hipStream_t stream) {
    const float* k    = (const float*)d_in[0];
    const float* v    = (const float*)d_in[1];
    const float* dt   = (const float*)d_in[2];
    const float* Bvec = (const float*)d_in[3];
    // d_in[4] = C_vec (unused by reference)
    const float* r    = (const float*)d_in[5];
    const float* g    = (const float*)d_in[6];
    const float* bd   = (const float*)d_in[7];
    const float* tf   = (const float*)d_in[8];

    float* out  = (float*)d_out;
    float* out2 = out + (size_t)B_SZ * L_SZ * H_SZ * D_SZ;

    float* Bs = (float*)d_ws;
    float* P  = Bs + B_SZ * L_SZ;
    float* Q  = P + (size_t)BH * C_CH * D_SZ;

    bs_kernel<<<dim3(B_SZ * L_SZ / 4), 256, 0, stream>>>(Bvec, Bs);
    phase1_mm<<<dim3(C_CH, BH), 256, 0, stream>>>(k, v, dt, Bs, bd, P, Q);
    phase2<<<dim3(BH, 4), 64, 0, stream>>>(P, Q, out2);
    phase3_mm<<<dim3(C_CH, BH), 256, 0, stream>>>(k, v, dt, r, g, Bs, bd, tf, Q, out);
}

// Round 3
// 118.018 us; speedup vs baseline: 1.9052x; 1.7365x over previous
//
#include <hip/hip_runtime.h>

// ParallelHybridScan: chunked linear scan reformulated as per-chunk matmuls.
// B=4 L=2048 H=16 D=64. Chunk T=64 -> C=32. BH=64 sequences.
// q~[t,k]=k*exp(-bd*cs[t,k]); k~[t,k]=Bs_t*k*exp(+bd*cs[t,k]); a_T=exp(-bd*cs[63,k])
// Phase1: Q_c = diag(a_T) * (K~^T V); P_c = a_T
// Phase2: sequential combine S_{c+1} = P_c*S_c + Q_c (overwrites Q with start states)
// Phase3: O = (q~ k~^T . causal) V + q~ S0; out = r*(O + tf*k*v)*g
//
// R3 changes vs R2: (a) no address-of-vector-element anywhere (R2 spilled 160MB
// of scratch: VALUBusy 0.7%, WRITE_SIZE 192MB); all matmul FMAs use explicit
// .x/.y/.z/.w. (b) tA/tD get col^((row&3)<<2) swizzle: their readers pull rows
// tr+16i (row bits 0-1 vary across lane groups) at a 64-float stride == same
// bank -> was 4-way conflict (8.4M cycles).

#define B_SZ 4
#define L_SZ 2048
#define H_SZ 16
#define D_SZ 64
#define N_SZ 64
#define T_CH 64
#define C_CH (L_SZ / T_CH)   // 32
#define BH (B_SZ * H_SZ)     // 64
#define STRIDE_T (H_SZ * D_SZ)

// swizzle for tiles whose readers differ in row bits 2-4 (tE: k~ / S0)
__device__ __forceinline__ int swz(int row, int col) {
    return col ^ (((row >> 2) & 7) << 2);
}
// swizzle for tiles whose readers differ in row bits 0-1 (tA, tD)
__device__ __forceinline__ int swzT(int row, int col) {
    return col ^ ((row & 3) << 2);
}

__global__ __launch_bounds__(256) void bs_kernel(const float* __restrict__ Bvec,
                                                 float* __restrict__ Bs) {
    int wid = (blockIdx.x * 256 + threadIdx.x) >> 6;
    int lane = threadIdx.x & 63;
    if (wid >= B_SZ * L_SZ) return;
    float s = Bvec[wid * N_SZ + lane];
    #pragma unroll
    for (int m = 32; m >= 1; m >>= 1) s += __shfl_xor(s, m, 64);
    if (lane == 0) Bs[wid] = s * (1.0f / 64.0f);
}

__global__ __launch_bounds__(256) void phase1_mm(
    const float* __restrict__ kq, const float* __restrict__ vq,
    const float* __restrict__ dq, const float* __restrict__ Bs,
    const float* __restrict__ bd, float* __restrict__ P, float* __restrict__ Q)
{
    int c = blockIdx.x, bh = blockIdx.y;
    int b = bh >> 4, h = bh & 15;
    int tid = threadIdx.x;
    alignas(16) __shared__ float tA[T_CH][D_SZ];  // dt -> csum
    alignas(16) __shared__ float tB[T_CH][D_SZ];  // k -> ktil
    alignas(16) __shared__ float tC[T_CH][D_SZ];  // v
    __shared__ float part[4][D_SZ];

    int t0 = c * T_CH;
    int q4 = (tid & 15) * 4;
    int tr = tid >> 4;
    size_t base = ((size_t)(b * L_SZ + t0) * H_SZ + h) * D_SZ;

    #pragma unroll
    for (int i = 0; i < 4; i++) {
        int t = tr + 16 * i;
        size_t off = base + (size_t)t * STRIDE_T + q4;
        *(float4*)&tA[t][q4] = *(const float4*)&dq[off];
        *(float4*)&tB[t][q4] = *(const float4*)&kq[off];
        *(float4*)&tC[t][q4] = *(const float4*)&vq[off];
    }
    __syncthreads();

    // inclusive cumsum along t, in place in tA (64 independent columns)
    {
        int k = tid & 63, qq = tid >> 6;
        float p = 0.f;
        #pragma unroll
        for (int t = 0; t < 16; t++) p += tA[qq * 16 + t][k];
        part[qq][k] = p;
        __syncthreads();
        float o = 0.f;
        #pragma unroll
        for (int j = 0; j < 3; j++) if (j < qq) o += part[j][k];
        #pragma unroll
        for (int t = 0; t < 16; t++) {
            o += tA[qq * 16 + t][k];
            tA[qq * 16 + t][k] = o;
        }
    }
    __syncthreads();

    // ktil in place over tB
    float4 bd4 = *(const float4*)&bd[h * D_SZ + q4];
    #pragma unroll
    for (int i = 0; i < 4; i++) {
        int t = tr + 16 * i;
        float bs = Bs[b * L_SZ + t0 + t];
        float4 cs = *(float4*)&tA[t][q4];
        float4 kk = *(float4*)&tB[t][q4];
        float4 kt;
        kt.x = bs * kk.x * __expf(bd4.x * cs.x);
        kt.y = bs * kk.y * __expf(bd4.y * cs.y);
        kt.z = bs * kk.z * __expf(bd4.z * cs.z);
        kt.w = bs * kk.w * __expf(bd4.w * cs.w);
        *(float4*)&tB[t][q4] = kt;
    }
    __syncthreads();

    // out[k][v] = aT[k] * sum_tau ktil[tau][k] * v[tau][v]
    float acc[4][4] = {};
    #pragma unroll 4
    for (int tau = 0; tau < T_CH; tau++) {
        float4 vv = *(const float4*)&tC[tau][q4];
        float kt0 = tB[tau][tr];
        float kt1 = tB[tau][tr + 16];
        float kt2 = tB[tau][tr + 32];
        float kt3 = tB[tau][tr + 48];
        acc[0][0] = fmaf(kt0, vv.x, acc[0][0]); acc[0][1] = fmaf(kt0, vv.y, acc[0][1]);
        acc[0][2] = fmaf(kt0, vv.z, acc[0][2]); acc[0][3] = fmaf(kt0, vv.w, acc[0][3]);
        acc[1][0] = fmaf(kt1, vv.x, acc[1][0]); acc[1][1] = fmaf(kt1, vv.y, acc[1][1]);
        acc[1][2] = fmaf(kt1, vv.z, acc[1][2]); acc[1][3] = fmaf(kt1, vv.w, acc[1][3]);
        acc[2][0] = fmaf(kt2, vv.x, acc[2][0]); acc[2][1] = fmaf(kt2, vv.y, acc[2][1]);
        acc[2][2] = fmaf(kt2, vv.z, acc[2][2]); acc[2][3] = fmaf(kt2, vv.w, acc[2][3]);
        acc[3][0] = fmaf(kt3, vv.x, acc[3][0]); acc[3][1] = fmaf(kt3, vv.y, acc[3][1]);
        acc[3][2] = fmaf(kt3, vv.z, acc[3][2]); acc[3][3] = fmaf(kt3, vv.w, acc[3][3]);
    }

    int kbase = h * D_SZ;
    #pragma unroll
    for (int i = 0; i < 4; i++) {
        int kr = tr + 16 * i;
        float aT = __expf(-bd[kbase + kr] * tA[63][kr]);
        float4 o;
        o.x = aT * acc[i][0]; o.y = aT * acc[i][1];
        o.z = aT * acc[i][2]; o.w = aT * acc[i][3];
        *(float4*)&Q[((size_t)(bh * C_CH + c) * D_SZ + kr) * D_SZ + q4] = o;
    }
    if (tid < D_SZ)
        P[(size_t)(bh * C_CH + c) * D_SZ + tid] = __expf(-bd[kbase + tid] * tA[63][tid]);
}

// Sequential combine over chunks; (bh, kq) blocks, 16 k-rows each.
__global__ __launch_bounds__(64) void phase2(const float* __restrict__ P,
                                             float* __restrict__ Q,
                                             float* __restrict__ out2) {
    int bh = blockIdx.x, kq = blockIdx.y;
    int lane = threadIdx.x;
    float S[16];
    #pragma unroll
    for (int i = 0; i < 16; i++) S[i] = 0.f;

    for (int c = 0; c < C_CH; c++) {
        size_t pb = (size_t)(bh * C_CH + c) * D_SZ + kq * 16;
        size_t qb = ((size_t)(bh * C_CH + c) * D_SZ + kq * 16) * D_SZ + lane;
        #pragma unroll
        for (int i = 0; i < 16; i++) {
            float p = P[pb + i];
            float q = Q[qb + i * D_SZ];
            Q[qb + i * D_SZ] = S[i];
            S[i] = fmaf(p, S[i], q);
        }
    }
    size_t ob = ((size_t)bh * D_SZ + kq * 16) * D_SZ + lane;
    #pragma unroll
    for (int i = 0; i < 16; i++) out2[ob + i * D_SZ] = S[i];
}

__global__ __launch_bounds__(256) void phase3_mm(
    const float* __restrict__ kq, const float* __restrict__ vq,
    const float* __restrict__ dq, const float* __restrict__ rq,
    const float* __restrict__ gq, const float* __restrict__ Bs,
    const float* __restrict__ bd, const float* __restrict__ tf,
    const float* __restrict__ Sstart, float* __restrict__ out)
{
    int c = blockIdx.x, bh = blockIdx.y;
    int b = bh >> 4, h = bh & 15;
    int tid = threadIdx.x;
    alignas(16) __shared__ float tA[T_CH][D_SZ];  // dt -> csum -> G(masked)  [swzT]
    alignas(16) __shared__ float tB[T_CH][D_SZ];  // k                        [linear]
    alignas(16) __shared__ float tC[T_CH][D_SZ];  // v                        [linear]
    alignas(16) __shared__ float tD[T_CH][D_SZ];  // csum partials -> qtil    [swzT]
    alignas(16) __shared__ float tE[T_CH][D_SZ];  // S0 -> ktil               [swz]

    int t0 = c * T_CH;
    int v4 = (tid & 15) * 4;
    int tr = tid >> 4;
    int sw2 = (tr & 3) << 2;           // swzT xor for rows tr+16*i
    size_t base = ((size_t)(b * L_SZ + t0) * H_SZ + h) * D_SZ;
    size_t sb = (size_t)(bh * C_CH + c) * D_SZ * D_SZ;

    #pragma unroll
    for (int i = 0; i < 4; i++) {
        int t = tr + 16 * i;
        size_t off = base + (size_t)t * STRIDE_T + v4;
        *(float4*)&tA[t][v4 ^ sw2] = *(const float4*)&dq[off];
        *(float4*)&tB[t][v4] = *(const float4*)&kq[off];
        *(float4*)&tC[t][v4] = *(const float4*)&vq[off];
        *(float4*)&tE[t][swz(t, v4)] = *(const float4*)&Sstart[sb + (size_t)t * D_SZ + v4];
    }
    __syncthreads();

    // inclusive cumsum along t in tA (swzT layout); partials staged in tD rows 0..3
    {
        int k = tid & 63, qq = tid >> 6;
        float p = 0.f;
        #pragma unroll
        for (int t = 0; t < 16; t++) p += tA[qq * 16 + t][k ^ ((t & 3) << 2)];
        tD[qq][k] = p;
        __syncthreads();
        float o = 0.f;
        #pragma unroll
        for (int j = 0; j < 3; j++) if (j < qq) o += tD[j][k];
        #pragma unroll
        for (int t = 0; t < 16; t++) {
            o += tA[qq * 16 + t][k ^ ((t & 3) << 2)];
            tA[qq * 16 + t][k ^ ((t & 3) << 2)] = o;
        }
    }
    __syncthreads();

    // qtil -> tD (swzT layout)
    float4 bd4 = *(const float4*)&bd[h * D_SZ + v4];
    #pragma unroll
    for (int i = 0; i < 4; i++) {
        int t = tr + 16 * i;
        float4 cs = *(float4*)&tA[t][v4 ^ sw2];
        float4 kk = *(float4*)&tB[t][v4];
        float4 qt;
        qt.x = kk.x * __expf(-bd4.x * cs.x);
        qt.y = kk.y * __expf(-bd4.y * cs.y);
        qt.z = kk.z * __expf(-bd4.z * cs.z);
        qt.w = kk.w * __expf(-bd4.w * cs.w);
        *(float4*)&tD[t][v4 ^ sw2] = qt;
    }
    __syncthreads();

    // matmul1: acc[t][v] += qtil[t][k] * S0[k][v]
    float acc[4][4] = {};
    for (int k4 = 0; k4 < D_SZ; k4 += 4) {
        float4 s0 = *(const float4*)&tE[k4 + 0][swz(k4 + 0, v4)];
        float4 s1 = *(const float4*)&tE[k4 + 1][swz(k4 + 1, v4)];
        float4 s2 = *(const float4*)&tE[k4 + 2][swz(k4 + 2, v4)];
        float4 s3 = *(const float4*)&tE[k4 + 3][swz(k4 + 3, v4)];
        #pragma unroll
        for (int i = 0; i < 4; i++) {
            float4 q = *(const float4*)&tD[tr + 16 * i][k4 ^ sw2];
            acc[i][0] = fmaf(q.x, s0.x, acc[i][0]);
            acc[i][0] = fmaf(q.y, s1.x, acc[i][0]);
            acc[i][0] = fmaf(q.z, s2.x, acc[i][0]);
            acc[i][0] = fmaf(q.w, s3.x, acc[i][0]);
            acc[i][1] = fmaf(q.x, s0.y, acc[i][1]);
            acc[i][1] = fmaf(q.y, s1.y, acc[i][1]);
            acc[i][1] = fmaf(q.z, s2.y, acc[i][1]);
            acc[i][1] = fmaf(q.w, s3.y, acc[i][1]);
            acc[i][2] = fmaf(q.x, s0.z, acc[i][2]);
            acc[i][2] = fmaf(q.y, s1.z, acc[i][2]);
            acc[i][2] = fmaf(q.z, s2.z, acc[i][2]);
            acc[i][2] = fmaf(q.w, s3.z, acc[i][2]);
            acc[i][3] = fmaf(q.x, s0.w, acc[i][3]);
            acc[i][3] = fmaf(q.y, s1.w, acc[i][3]);
            acc[i][3] = fmaf(q.z, s2.w, acc[i][3]);
            acc[i][3] = fmaf(q.w, s3.w, acc[i][3]);
        }
    }
    __syncthreads();   // done reading tE (S0)

    // ktil -> tE (swz layout)
    #pragma unroll
    for (int i = 0; i < 4; i++) {
        int t = tr + 16 * i;
        float bs = Bs[b * L_SZ + t0 + t];
        float4 cs = *(float4*)&tA[t][v4 ^ sw2];
        float4 kk = *(float4*)&tB[t][v4];
        float4 kt;
        kt.x = bs * kk.x * __expf(bd4.x * cs.x);
        kt.y = bs * kk.y * __expf(bd4.y * cs.y);
        kt.z = bs * kk.z * __expf(bd4.z * cs.z);
        kt.w = bs * kk.w * __expf(bd4.w * cs.w);
        *(float4*)&tE[t][swz(t, v4)] = kt;
    }
    __syncthreads();

    // G[t][tau] = sum_k qtil[t][k]*ktil[tau][k]; masked -> tA (swzT)
    float g[4][4] = {};
    for (int k4 = 0; k4 < D_SZ; k4 += 4) {
        float4 kb0 = *(const float4*)&tE[v4 + 0][swz(v4 + 0, k4)];
        float4 kb1 = *(const float4*)&tE[v4 + 1][swz(v4 + 1, k4)];
        float4 kb2 = *(const float4*)&tE[v4 + 2][swz(v4 + 2, k4)];
        float4 kb3 = *(const float4*)&tE[v4 + 3][swz(v4 + 3, k4)];
        #pragma unroll
        for (int i = 0; i < 4; i++) {
            float4 q = *(const float4*)&tD[tr + 16 * i][k4 ^ sw2];
            g[i][0] = fmaf(q.x, kb0.x, g[i][0]);
            g[i][0] = fmaf(q.y, kb0.y, g[i][0]);
            g[i][0] = fmaf(q.z, kb0.z, g[i][0]);
            g[i][0] = fmaf(q.w, kb0.w, g[i][0]);
            g[i][1] = fmaf(q.x, kb1.x, g[i][1]);
            g[i][1] = fmaf(q.y, kb1.y, g[i][1]);
            g[i][1] = fmaf(q.z, kb1.z, g[i][1]);
            g[i][1] = fmaf(q.w, kb1.w, g[i][1]);
            g[i][2] = fmaf(q.x, kb2.x, g[i][2]);
            g[i][2] = fmaf(q.y, kb2.y, g[i][2]);
            g[i][2] = fmaf(q.z, kb2.z, g[i][2]);
            g[i][2] = fmaf(q.w, kb2.w, g[i][2]);
            g[i][3] = fmaf(q.x, kb3.x, g[i][3]);
            g[i][3] = fmaf(q.y, kb3.y, g[i][3]);
            g[i][3] = fmaf(q.z, kb3.z, g[i][3]);
            g[i][3] = fmaf(q.w, kb3.w, g[i][3]);
        }
    }
    #pragma unroll
    for (int i = 0; i < 4; i++) {
        int t = tr + 16 * i;
        float4 gm;
        gm.x = (v4 + 0 <= t) ? g[i][0] : 0.f;
        gm.y = (v4 + 1 <= t) ? g[i][1] : 0.f;
        gm.z = (v4 + 2 <= t) ? g[i][2] : 0.f;
        gm.w = (v4 + 3 <= t) ? g[i][3] : 0.f;
        *(float4*)&tA[t][v4 ^ sw2] = gm;
    }
    __syncthreads();

    // matmul2: acc[t][v] += G[t][tau] * v[tau][v]
    for (int p4 = 0; p4 < T_CH; p4 += 4) {
        float4 v0 = *(const float4*)&tC[p4 + 0][v4];
        float4 v1 = *(const float4*)&tC[p4 + 1][v4];
        float4 v2 = *(const float4*)&tC[p4 + 2][v4];
        float4 v3 = *(const float4*)&tC[p4 + 3][v4];
        #pragma unroll
        for (int i = 0; i < 4; i++) {
            float4 ga = *(const float4*)&tA[tr + 16 * i][p4 ^ sw2];
            acc[i][0] = fmaf(ga.x, v0.x, acc[i][0]);
            acc[i][0] = fmaf(ga.y, v1.x, acc[i][0]);
            acc[i][0] = fmaf(ga.z, v2.x, acc[i][0]);
            acc[i][0] = fmaf(ga.w, v3.x, acc[i][0]);
            acc[i][1] = fmaf(ga.x, v0.y, acc[i][1]);
            acc[i][1] = fmaf(ga.y, v1.y, acc[i][1]);
            acc[i][1] = fmaf(ga.z, v2.y, acc[i][1]);
            acc[i][1] = fmaf(ga.w, v3.y, acc[i][1]);
            acc[i][2] = fmaf(ga.x, v0.z, acc[i][2]);
            acc[i][2] = fmaf(ga.y, v1.z, acc[i][2]);
            acc[i][2] = fmaf(ga.z, v2.z, acc[i][2]);
            acc[i][2] = fmaf(ga.w, v3.z, acc[i][2]);
            acc[i][3] = fmaf(ga.x, v0.w, acc[i][3]);
            acc[i][3] = fmaf(ga.y, v1.w, acc[i][3]);
            acc[i][3] = fmaf(ga.z, v2.w, acc[i][3]);
            acc[i][3] = fmaf(ga.w, v3.w, acc[i][3]);
        }
    }

    // epilogue: out = r * (acc + tf*k*v) * g
    float4 tf4 = *(const float4*)&tf[h * D_SZ + v4];
    #pragma unroll
    for (int i = 0; i < 4; i++) {
        int t = tr + 16 * i;
        size_t off = base + (size_t)t * STRIDE_T + v4;
        float4 r4 = *(const float4*)&rq[off];
        float4 g4 = *(const float4*)&gq[off];
        float4 kk = *(float4*)&tB[t][v4];
        float4 vv = *(const float4*)&tC[t][v4];
        float4 o;
        o.x = r4.x * fmaf(tf4.x, kk.x * vv.x, acc[i][0]) * g4.x;
        o.y = r4.y * fmaf(tf4.y, kk.y * vv.y, acc[i][1]) * g4.y;
        o.z = r4.z * fmaf(tf4.z, kk.z * vv.z, acc[i][2]) * g4.z;
        o.w = r4.w * fmaf(tf4.w, kk.w * vv.w, acc[i][3]) * g4.w;
        *(float4*)&out[off] = o;
    }
}

extern "C" void kernel_launch(void* const* d_in, const int* in_sizes, int n_in,
                              void* d_out, int out_size, void* d_ws, size_t ws_size,
                              hipStream_t stream) {
    const float* k    = (const float*)d_in[0];
    const float* v    = (const float*)d_in[1];
    const float* dt   = (const float*)d_in[2];
    const float* Bvec = (const float*)d_in[3];
    // d_in[4] = C_vec (unused by reference)
    const float* r    = (const float*)d_in[5];
    const float* g    = (const float*)d_in[6];
    const float* bd   = (const float*)d_in[7];
    const float* tf   = (const float*)d_in[8];

    float* out  = (float*)d_out;
    float* out2 = out + (size_t)B_SZ * L_SZ * H_SZ * D_SZ;

    float* Bs = (float*)d_ws;
    float* P  = Bs + B_SZ * L_SZ;
    float* Q  = P + (size_t)BH * C_CH * D_SZ;

    bs_kernel<<<dim3(B_SZ * L_SZ / 4), 256, 0, stream>>>(Bvec, Bs);
    phase1_mm<<<dim3(C_CH, BH), 256, 0, stream>>>(k, v, dt, Bs, bd, P, Q);
    phase2<<<dim3(BH, 4), 64, 0, stream>>>(P, Q, out2);
    phase3_mm<<<dim3(C_CH, BH), 256, 0, stream>>>(k, v, dt, r, g, Bs, bd, tf, Q, out);
}

// Round 4
// 113.919 us; speedup vs baseline: 1.9738x; 1.0360x over previous
//
#include <hip/hip_runtime.h>

// ParallelHybridScan: chunked linear scan as per-chunk matmuls. fp32 exact.
// B=4 L=2048 H=16 D=64. Chunk T=64 -> C=32. BH=64.
// q~[t,k]=k*exp(-bd*cs[t,k]); k~[t,k]=Bs_t*k*exp(+bd*cs[t,k]); aT=exp(-bd*cs[63,k])
// Phase1: Q_c = diag(aT)*(K~^T V); P_c = aT
// Phase2: S_{c+1} = P_c*S_c + Q_c (overwrites Q with chunk-start states)
// Phase3: O = (q~ k~^T . causal) V + q~ S0; out = r*(O + tf*k*v)*g
//
// R4 vs R3: phase3 LDS 80KB->49.25KB (3 blocks/CU, was 2): cumsum done in a
// per-column register pass reading dt/k straight from global (coalesced), qtil
// written directly, ktil stashed in 16 regs until S0 tile is free, G overwrites
// qtil tile; epilogue re-reads k from global (L3-hot). tV swizzled (was the
// remaining 2.1M bank-conflict cycles). Phase1 LDS 33KB (4 blocks/CU).
// Phase2 register-double-buffer prefetch.

#define B_SZ 4
#define L_SZ 2048
#define H_SZ 16
#define D_SZ 64
#define N_SZ 64
#define T_CH 64
#define C_CH (L_SZ / T_CH)   // 32
#define BH (B_SZ * H_SZ)     // 64
#define STRIDE_T (H_SZ * D_SZ)

// swizzle for tiles whose readers differ in row bits 2-4 (tK: S0 / k~)
__device__ __forceinline__ int swz(int row, int col) {
    return col ^ (((row >> 2) & 7) << 2);
}

__global__ __launch_bounds__(256) void bs_kernel(const float* __restrict__ Bvec,
                                                 float* __restrict__ Bs) {
    int wid = (blockIdx.x * 256 + threadIdx.x) >> 6;
    int lane = threadIdx.x & 63;
    if (wid >= B_SZ * L_SZ) return;
    float s = Bvec[wid * N_SZ + lane];
    #pragma unroll
    for (int m = 32; m >= 1; m >>= 1) s += __shfl_xor(s, m, 64);
    if (lane == 0) Bs[wid] = s * (1.0f / 64.0f);
}

__global__ __launch_bounds__(256, 4) void phase1_mm(
    const float* __restrict__ kq, const float* __restrict__ vq,
    const float* __restrict__ dq, const float* __restrict__ Bs,
    const float* __restrict__ bd, float* __restrict__ P, float* __restrict__ Q)
{
    int c = blockIdx.x, bh = blockIdx.y;
    int b = bh >> 4, h = bh & 15;
    int tid = threadIdx.x;
    alignas(16) __shared__ float tKt[T_CH][D_SZ];  // k~ [tau][k], linear (row-uniform readers)
    alignas(16) __shared__ float tV[T_CH][D_SZ];   // v, linear (row-uniform readers)
    __shared__ float part[4][D_SZ];
    __shared__ float aTs[D_SZ];

    int t0 = c * T_CH;
    int q4 = (tid & 15) * 4;
    int tr = tid >> 4;
    size_t base = ((size_t)(b * L_SZ + t0) * H_SZ + h) * D_SZ;

    #pragma unroll
    for (int i = 0; i < 4; i++) {
        int t = tr + 16 * i;
        *(float4*)&tV[t][q4] = *(const float4*)&vq[base + (size_t)t * STRIDE_T + q4];
    }

    // per-column cumsum pass: thread owns column kcol, rows qq*16..qq*16+15
    int kcol = tid & 63, qq = tid >> 6;
    float dts[16], kin[16], bsv[16];
    #pragma unroll
    for (int j = 0; j < 16; j++) {
        int t = qq * 16 + j;
        dts[j] = dq[base + (size_t)t * STRIDE_T + kcol];
        kin[j] = kq[base + (size_t)t * STRIDE_T + kcol];
        bsv[j] = Bs[b * L_SZ + t0 + t];
    }
    float psum = 0.f;
    #pragma unroll
    for (int j = 0; j < 16; j++) psum += dts[j];
    part[qq][kcol] = psum;
    __syncthreads();

    float cs = 0.f;
    {
        float p0 = part[0][kcol], p1 = part[1][kcol], p2 = part[2][kcol];
        if (qq > 0) cs += p0;
        if (qq > 1) cs += p1;
        if (qq > 2) cs += p2;
    }
    float bdk = bd[h * D_SZ + kcol];
    #pragma unroll
    for (int j = 0; j < 16; j++) {
        int t = qq * 16 + j;
        cs += dts[j];
        tKt[t][kcol] = bsv[j] * kin[j] * __expf(bdk * cs);
    }
    if (qq == 3) aTs[kcol] = __expf(-bdk * cs);
    __syncthreads();

    // out[k][v] = aT[k] * sum_tau ktil[tau][k] * v[tau][v]
    float acc[4][4] = {};
    #pragma unroll 4
    for (int tau = 0; tau < T_CH; tau++) {
        float4 vv = *(const float4*)&tV[tau][q4];
        float kt0 = tKt[tau][tr];
        float kt1 = tKt[tau][tr + 16];
        float kt2 = tKt[tau][tr + 32];
        float kt3 = tKt[tau][tr + 48];
        acc[0][0] = fmaf(kt0, vv.x, acc[0][0]); acc[0][1] = fmaf(kt0, vv.y, acc[0][1]);
        acc[0][2] = fmaf(kt0, vv.z, acc[0][2]); acc[0][3] = fmaf(kt0, vv.w, acc[0][3]);
        acc[1][0] = fmaf(kt1, vv.x, acc[1][0]); acc[1][1] = fmaf(kt1, vv.y, acc[1][1]);
        acc[1][2] = fmaf(kt1, vv.z, acc[1][2]); acc[1][3] = fmaf(kt1, vv.w, acc[1][3]);
        acc[2][0] = fmaf(kt2, vv.x, acc[2][0]); acc[2][1] = fmaf(kt2, vv.y, acc[2][1]);
        acc[2][2] = fmaf(kt2, vv.z, acc[2][2]); acc[2][3] = fmaf(kt2, vv.w, acc[2][3]);
        acc[3][0] = fmaf(kt3, vv.x, acc[3][0]); acc[3][1] = fmaf(kt3, vv.y, acc[3][1]);
        acc[3][2] = fmaf(kt3, vv.z, acc[3][2]); acc[3][3] = fmaf(kt3, vv.w, acc[3][3]);
    }

    #pragma unroll
    for (int i = 0; i < 4; i++) {
        int kr = tr + 16 * i;
        float aT = aTs[kr];
        float4 o;
        o.x = aT * acc[i][0]; o.y = aT * acc[i][1];
        o.z = aT * acc[i][2]; o.w = aT * acc[i][3];
        *(float4*)&Q[((size_t)(bh * C_CH + c) * D_SZ + kr) * D_SZ + q4] = o;
    }
    if (tid < D_SZ)
        P[(size_t)(bh * C_CH + c) * D_SZ + tid] = aTs[tid];
}

// Sequential combine over chunks with register double-buffer prefetch.
__global__ __launch_bounds__(64) void phase2(const float* __restrict__ P,
                                             float* __restrict__ Qrw,
                                             float* __restrict__ out2) {
    int bh = blockIdx.x, kqi = blockIdx.y;
    int lane = threadIdx.x;
    float S[16];
    #pragma unroll
    for (int i = 0; i < 16; i++) S[i] = 0.f;

    size_t pb = (size_t)bh * C_CH * D_SZ + kqi * 16;
    size_t qb = ((size_t)bh * C_CH * D_SZ + kqi * 16) * D_SZ + lane;
    const size_t qstep = (size_t)D_SZ * D_SZ;

    float pc[16], qc[16];
    #pragma unroll
    for (int i = 0; i < 16; i++) {
        pc[i] = P[pb + i];
        qc[i] = Qrw[qb + (size_t)i * D_SZ];
    }
    for (int c = 0; c < C_CH; c++) {
        float pn[16] = {}, qn[16] = {};
        if (c < C_CH - 1) {
            #pragma unroll
            for (int i = 0; i < 16; i++) {
                pn[i] = P[pb + (size_t)(c + 1) * D_SZ + i];
                qn[i] = Qrw[qb + (size_t)(c + 1) * qstep + (size_t)i * D_SZ];
            }
        }
        #pragma unroll
        for (int i = 0; i < 16; i++) {
            Qrw[qb + (size_t)c * qstep + (size_t)i * D_SZ] = S[i];
            S[i] = fmaf(pc[i], S[i], qc[i]);
            pc[i] = pn[i]; qc[i] = qn[i];
        }
    }
    size_t ob = ((size_t)bh * D_SZ + kqi * 16) * D_SZ + lane;
    #pragma unroll
    for (int i = 0; i < 16; i++) out2[ob + (size_t)i * D_SZ] = S[i];
}

__global__ __launch_bounds__(256, 3) void phase3_mm(
    const float* __restrict__ kq, const float* __restrict__ vq,
    const float* __restrict__ dq, const float* __restrict__ rq,
    const float* __restrict__ gq, const float* __restrict__ Bs,
    const float* __restrict__ bd, const float* __restrict__ tf,
    const float* __restrict__ Sstart, float* __restrict__ out)
{
    int c = blockIdx.x, bh = blockIdx.y;
    int b = bh >> 4, h = bh & 15;
    int tid = threadIdx.x;
    alignas(16) __shared__ float tV[T_CH][D_SZ];   // v       [col ^ ((row&3)<<2)]
    alignas(16) __shared__ float tQ[T_CH][D_SZ];   // q~ -> G [col ^ ((row&3)<<2)]
    alignas(16) __shared__ float tK[T_CH][D_SZ];   // S0 -> k~ [swz: row>>2]
    __shared__ float part[4][D_SZ];

    int t0 = c * T_CH;
    int v4 = (tid & 15) * 4;
    int tr = tid >> 4;
    int sw2 = (tr & 3) << 2;
    size_t base = ((size_t)(b * L_SZ + t0) * H_SZ + h) * D_SZ;
    size_t sb = (size_t)(bh * C_CH + c) * D_SZ * D_SZ;

    #pragma unroll
    for (int i = 0; i < 4; i++) {
        int t = tr + 16 * i;
        *(float4*)&tV[t][v4 ^ sw2] = *(const float4*)&vq[base + (size_t)t * STRIDE_T + v4];
        *(float4*)&tK[t][swz(t, v4)] = *(const float4*)&Sstart[sb + (size_t)t * D_SZ + v4];
    }

    // per-column cumsum pass
    int kcol = tid & 63, qq = tid >> 6;
    float dts[16], kin[16], bsv[16];
    #pragma unroll
    for (int j = 0; j < 16; j++) {
        int t = qq * 16 + j;
        dts[j] = dq[base + (size_t)t * STRIDE_T + kcol];
        kin[j] = kq[base + (size_t)t * STRIDE_T + kcol];
        bsv[j] = Bs[b * L_SZ + t0 + t];
    }
    float psum = 0.f;
    #pragma unroll
    for (int j = 0; j < 16; j++) psum += dts[j];
    part[qq][kcol] = psum;
    __syncthreads();                                     // B1

    float cs = 0.f;
    {
        float p0 = part[0][kcol], p1 = part[1][kcol], p2 = part[2][kcol];
        if (qq > 0) cs += p0;
        if (qq > 1) cs += p1;
        if (qq > 2) cs += p2;
    }
    float bdk = bd[h * D_SZ + kcol];
    float ktl[16];
    #pragma unroll
    for (int j = 0; j < 16; j++) {
        int t = qq * 16 + j;
        cs += dts[j];
        tQ[t][kcol ^ ((j & 3) << 2)] = kin[j] * __expf(-bdk * cs);  // t&3 == j&3
        ktl[j] = bsv[j] * kin[j] * __expf(bdk * cs);
    }
    __syncthreads();                                     // B2

    // matmul1: acc[t][v] += qtil[t][k] * S0[k][v]
    float acc[4][4] = {};
    for (int k4 = 0; k4 < D_SZ; k4 += 4) {
        float4 s0 = *(const float4*)&tK[k4 + 0][swz(k4 + 0, v4)];
        float4 s1 = *(const float4*)&tK[k4 + 1][swz(k4 + 1, v4)];
        float4 s2 = *(const float4*)&tK[k4 + 2][swz(k4 + 2, v4)];
        float4 s3 = *(const float4*)&tK[k4 + 3][swz(k4 + 3, v4)];
        #pragma unroll
        for (int i = 0; i < 4; i++) {
            float4 q = *(const float4*)&tQ[tr + 16 * i][k4 ^ sw2];
            acc[i][0] = fmaf(q.x, s0.x, acc[i][0]);
            acc[i][0] = fmaf(q.y, s1.x, acc[i][0]);
            acc[i][0] = fmaf(q.z, s2.x, acc[i][0]);
            acc[i][0] = fmaf(q.w, s3.x, acc[i][0]);
            acc[i][1] = fmaf(q.x, s0.y, acc[i][1]);
            acc[i][1] = fmaf(q.y, s1.y, acc[i][1]);
            acc[i][1] = fmaf(q.z, s2.y, acc[i][1]);
            acc[i][1] = fmaf(q.w, s3.y, acc[i][1]);
            acc[i][2] = fmaf(q.x, s0.z, acc[i][2]);
            acc[i][2] = fmaf(q.y, s1.z, acc[i][2]);
            acc[i][2] = fmaf(q.z, s2.z, acc[i][2]);
            acc[i][2] = fmaf(q.w, s3.z, acc[i][2]);
            acc[i][3] = fmaf(q.x, s0.w, acc[i][3]);
            acc[i][3] = fmaf(q.y, s1.w, acc[i][3]);
            acc[i][3] = fmaf(q.z, s2.w, acc[i][3]);
            acc[i][3] = fmaf(q.w, s3.w, acc[i][3]);
        }
    }
    __syncthreads();                                     // B3: S0 readers done

    #pragma unroll
    for (int j = 0; j < 16; j++) {
        int t = qq * 16 + j;
        tK[t][swz(t, kcol)] = ktl[j];
    }
    __syncthreads();                                     // B4

    // G[t][tau] = sum_k qtil[t][k]*ktil[tau][k]
    float g[4][4] = {};
    for (int k4 = 0; k4 < D_SZ; k4 += 4) {
        float4 kb0 = *(const float4*)&tK[v4 + 0][swz(v4 + 0, k4)];
        float4 kb1 = *(const float4*)&tK[v4 + 1][swz(v4 + 1, k4)];
        float4 kb2 = *(const float4*)&tK[v4 + 2][swz(v4 + 2, k4)];
        float4 kb3 = *(const float4*)&tK[v4 + 3][swz(v4 + 3, k4)];
        #pragma unroll
        for (int i = 0; i < 4; i++) {
            float4 q = *(const float4*)&tQ[tr + 16 * i][k4 ^ sw2];
            g[i][0] = fmaf(q.x, kb0.x, g[i][0]);
            g[i][0] = fmaf(q.y, kb0.y, g[i][0]);
            g[i][0] = fmaf(q.z, kb0.z, g[i][0]);
            g[i][0] = fmaf(q.w, kb0.w, g[i][0]);
            g[i][1] = fmaf(q.x, kb1.x, g[i][1]);
            g[i][1] = fmaf(q.y, kb1.y, g[i][1]);
            g[i][1] = fmaf(q.z, kb1.z, g[i][1]);
            g[i][1] = fmaf(q.w, kb1.w, g[i][1]);
            g[i][2] = fmaf(q.x, kb2.x, g[i][2]);
            g[i][2] = fmaf(q.y, kb2.y, g[i][2]);
            g[i][2] = fmaf(q.z, kb2.z, g[i][2]);
            g[i][2] = fmaf(q.w, kb2.w, g[i][2]);
            g[i][3] = fmaf(q.x, kb3.x, g[i][3]);
            g[i][3] = fmaf(q.y, kb3.y, g[i][3]);
            g[i][3] = fmaf(q.z, kb3.z, g[i][3]);
            g[i][3] = fmaf(q.w, kb3.w, g[i][3]);
        }
    }
    __syncthreads();                                     // B5: qtil readers done
    #pragma unroll
    for (int i = 0; i < 4; i++) {
        int t = tr + 16 * i;
        float4 gm;
        gm.x = (v4 + 0 <= t) ? g[i][0] : 0.f;
        gm.y = (v4 + 1 <= t) ? g[i][1] : 0.f;
        gm.z = (v4 + 2 <= t) ? g[i][2] : 0.f;
        gm.w = (v4 + 3 <= t) ? g[i][3] : 0.f;
        *(float4*)&tQ[t][v4 ^ sw2] = gm;
    }
    __syncthreads();                                     // B6

    // epilogue loads issued early, consumed after matmul2
    float4 r4[4], g4[4], kk4[4];
    #pragma unroll
    for (int i = 0; i < 4; i++) {
        int t = tr + 16 * i;
        size_t off = base + (size_t)t * STRIDE_T + v4;
        r4[i] = *(const float4*)&rq[off];
        g4[i] = *(const float4*)&gq[off];
        kk4[i] = *(const float4*)&kq[off];
    }

    // matmul2: acc[t][v] += G[t][tau] * v[tau][v]
    for (int p4 = 0; p4 < T_CH; p4 += 4) {
        float4 v0 = *(const float4*)&tV[p4 + 0][v4 ^ 0];
        float4 v1 = *(const float4*)&tV[p4 + 1][v4 ^ 4];
        float4 v2 = *(const float4*)&tV[p4 + 2][v4 ^ 8];
        float4 v3 = *(const float4*)&tV[p4 + 3][v4 ^ 12];
        #pragma unroll
        for (int i = 0; i < 4; i++) {
            float4 ga = *(const float4*)&tQ[tr + 16 * i][p4 ^ sw2];
            acc[i][0] = fmaf(ga.x, v0.x, acc[i][0]);
            acc[i][0] = fmaf(ga.y, v1.x, acc[i][0]);
            acc[i][0] = fmaf(ga.z, v2.x, acc[i][0]);
            acc[i][0] = fmaf(ga.w, v3.x, acc[i][0]);
            acc[i][1] = fmaf(ga.x, v0.y, acc[i][1]);
            acc[i][1] = fmaf(ga.y, v1.y, acc[i][1]);
            acc[i][1] = fmaf(ga.z, v2.y, acc[i][1]);
            acc[i][1] = fmaf(ga.w, v3.y, acc[i][1]);
            acc[i][2] = fmaf(ga.x, v0.z, acc[i][2]);
            acc[i][2] = fmaf(ga.y, v1.z, acc[i][2]);
            acc[i][2] = fmaf(ga.z, v2.z, acc[i][2]);
            acc[i][2] = fmaf(ga.w, v3.z, acc[i][2]);
            acc[i][3] = fmaf(ga.x, v0.w, acc[i][3]);
            acc[i][3] = fmaf(ga.y, v1.w, acc[i][3]);
            acc[i][3] = fmaf(ga.z, v2.w, acc[i][3]);
            acc[i][3] = fmaf(ga.w, v3.w, acc[i][3]);
        }
    }

    float4 tf4 = *(const float4*)&tf[h * D_SZ + v4];
    #pragma unroll
    for (int i = 0; i < 4; i++) {
        int t = tr + 16 * i;
        size_t off = base + (size_t)t * STRIDE_T + v4;
        float4 vv = *(const float4*)&tV[t][v4 ^ sw2];
        float4 o;
        o.x = r4[i].x * fmaf(tf4.x, kk4[i].x * vv.x, acc[i][0]) * g4[i].x;
        o.y = r4[i].y * fmaf(tf4.y, kk4[i].y * vv.y, acc[i][1]) * g4[i].y;
        o.z = r4[i].z * fmaf(tf4.z, kk4[i].z * vv.z, acc[i][2]) * g4[i].z;
        o.w = r4[i].w * fmaf(tf4.w, kk4[i].w * vv.w, acc[i][3]) * g4[i].w;
        *(float4*)&out[off] = o;
    }
}

extern "C" void kernel_launch(void* const* d_in, const int* in_sizes, int n_in,
                              void* d_out, int out_size, void* d_ws, size_t ws_size,
                              hipStream_t stream) {
    const float* k    = (const float*)d_in[0];
    const float* v    = (const float*)d_in[1];
    const float* dt   = (const float*)d_in[2];
    const float* Bvec = (const float*)d_in[3];
    // d_in[4] = C_vec (unused by reference)
    const float* r    = (const float*)d_in[5];
    const float* g    = (const float*)d_in[6];
    const float* bd   = (const float*)d_in[7];
    const float* tf   = (const float*)d_in[8];

    float* out  = (float*)d_out;
    float* out2 = out + (size_t)B_SZ * L_SZ * H_SZ * D_SZ;

    float* Bs = (float*)d_ws;
    float* P  = Bs + B_SZ * L_SZ;
    float* Q  = P + (size_t)BH * C_CH * D_SZ;

    bs_kernel<<<dim3(B_SZ * L_SZ / 4), 256, 0, stream>>>(Bvec, Bs);
    phase1_mm<<<dim3(C_CH, BH), 256, 0, stream>>>(k, v, dt, Bs, bd, P, Q);
    phase2<<<dim3(BH, 4), 64, 0, stream>>>(P, Q, out2);
    phase3_mm<<<dim3(C_CH, BH), 256, 0, stream>>>(k, v, dt, r, g, Bs, bd, tf, Q, out);
}

// Round 5
// 99.090 us; speedup vs baseline: 2.2692x; 1.1496x over previous
//
#include <hip/hip_runtime.h>

// ParallelHybridScan: chunked linear scan as per-chunk matmuls. B=4 L=2048 H=16 D=64.
// q~[t,k]=k*exp(-bd*cs[t,k]); k~[t,k]=Bs_t*k*exp(+bd*cs[t,k]); aT=exp(-bd*cs[63,k])
// Phase1: Q_c = diag(aT)*(K~^T V); P_c = aT
// Phase2: S_{c+1} = P_c*S_c + Q_c (overwrites Q with chunk-start states)
// Phase3 (MFMA): G = q~ k~^T (masked causal); O = G V + q~ S0; out = r*(O+tf*k*v)*g
//
// R5: phase3 matmuls on MFMA 16x16x32 bf16, fp32 accum. All operands stored
// row-major-along-K as bf16 LDS tiles (X*Y^T idiom: A-frag and B-frag are the
// same contiguous 16B read). S0,V staged transposed via u16 scatter. G
// overwrites k~ tile. LDS 33.8KB -> 4 blocks/CU. bf16 error is relative, so
// exp dynamic range is harmless; masked upper-triangle stays finite.

#define B_SZ 4
#define L_SZ 2048
#define H_SZ 16
#define D_SZ 64
#define N_SZ 64
#define T_CH 64
#define C_CH (L_SZ / T_CH)   // 32
#define BH (B_SZ * H_SZ)     // 64
#define STRIDE_T (H_SZ * D_SZ)

typedef short short8 __attribute__((ext_vector_type(8)));
typedef float f32x4 __attribute__((ext_vector_type(4)));

// bf16 tile: ushort[64][64] with 16B-block XOR swizzle (G4: byte ^= (row&7)<<4)
#define SWZ(row, col) (((row) << 6) + ((col) ^ (((row) & 7) << 3)))

__device__ __forceinline__ ushort f2bf(float x) {
    unsigned u = __float_as_uint(x);
    u += 0x7FFFu + ((u >> 16) & 1u);   // round-to-nearest-even
    return (ushort)(u >> 16);
}

__global__ __launch_bounds__(256) void bs_kernel(const float* __restrict__ Bvec,
                                                 float* __restrict__ Bs) {
    int wid = (blockIdx.x * 256 + threadIdx.x) >> 6;
    int lane = threadIdx.x & 63;
    if (wid >= B_SZ * L_SZ) return;
    float s = Bvec[wid * N_SZ + lane];
    #pragma unroll
    for (int m = 32; m >= 1; m >>= 1) s += __shfl_xor(s, m, 64);
    if (lane == 0) Bs[wid] = s * (1.0f / 64.0f);
}

__global__ __launch_bounds__(256) void phase1_mm(
    const float* __restrict__ kq, const float* __restrict__ vq,
    const float* __restrict__ dq, const float* __restrict__ Bs,
    const float* __restrict__ bd, float* __restrict__ P, float* __restrict__ Q)
{
    int c = blockIdx.x, bh = blockIdx.y;
    int b = bh >> 4, h = bh & 15;
    int tid = threadIdx.x;
    alignas(16) __shared__ float tKt[T_CH][D_SZ];  // k~ [tau][k]
    alignas(16) __shared__ float tV[T_CH][D_SZ];   // v
    __shared__ float part[4][D_SZ];
    __shared__ float aTs[D_SZ];

    int t0 = c * T_CH;
    int q4 = (tid & 15) * 4;
    int tr = tid >> 4;
    size_t base = ((size_t)(b * L_SZ + t0) * H_SZ + h) * D_SZ;

    #pragma unroll
    for (int i = 0; i < 4; i++) {
        int t = tr + 16 * i;
        *(float4*)&tV[t][q4] = *(const float4*)&vq[base + (size_t)t * STRIDE_T + q4];
    }

    int kcol = tid & 63, qq = tid >> 6;
    float dts[16], kin[16], bsv[16];
    #pragma unroll
    for (int j = 0; j < 16; j++) {
        int t = qq * 16 + j;
        dts[j] = dq[base + (size_t)t * STRIDE_T + kcol];
        kin[j] = kq[base + (size_t)t * STRIDE_T + kcol];
        bsv[j] = Bs[b * L_SZ + t0 + t];
    }
    float psum = 0.f;
    #pragma unroll
    for (int j = 0; j < 16; j++) psum += dts[j];
    part[qq][kcol] = psum;
    __syncthreads();

    float cs = 0.f;
    {
        float p0 = part[0][kcol], p1 = part[1][kcol], p2 = part[2][kcol];
        if (qq > 0) cs += p0;
        if (qq > 1) cs += p1;
        if (qq > 2) cs += p2;
    }
    float bdk = bd[h * D_SZ + kcol];
    #pragma unroll
    for (int j = 0; j < 16; j++) {
        int t = qq * 16 + j;
        cs += dts[j];
        tKt[t][kcol] = bsv[j] * kin[j] * __expf(bdk * cs);
    }
    if (qq == 3) aTs[kcol] = __expf(-bdk * cs);
    __syncthreads();

    float acc[4][4] = {};
    #pragma unroll 4
    for (int tau = 0; tau < T_CH; tau++) {
        float4 vv = *(const float4*)&tV[tau][q4];
        float kt0 = tKt[tau][tr];
        float kt1 = tKt[tau][tr + 16];
        float kt2 = tKt[tau][tr + 32];
        float kt3 = tKt[tau][tr + 48];
        acc[0][0] = fmaf(kt0, vv.x, acc[0][0]); acc[0][1] = fmaf(kt0, vv.y, acc[0][1]);
        acc[0][2] = fmaf(kt0, vv.z, acc[0][2]); acc[0][3] = fmaf(kt0, vv.w, acc[0][3]);
        acc[1][0] = fmaf(kt1, vv.x, acc[1][0]); acc[1][1] = fmaf(kt1, vv.y, acc[1][1]);
        acc[1][2] = fmaf(kt1, vv.z, acc[1][2]); acc[1][3] = fmaf(kt1, vv.w, acc[1][3]);
        acc[2][0] = fmaf(kt2, vv.x, acc[2][0]); acc[2][1] = fmaf(kt2, vv.y, acc[2][1]);
        acc[2][2] = fmaf(kt2, vv.z, acc[2][2]); acc[2][3] = fmaf(kt2, vv.w, acc[2][3]);
        acc[3][0] = fmaf(kt3, vv.x, acc[3][0]); acc[3][1] = fmaf(kt3, vv.y, acc[3][1]);
        acc[3][2] = fmaf(kt3, vv.z, acc[3][2]); acc[3][3] = fmaf(kt3, vv.w, acc[3][3]);
    }

    #pragma unroll
    for (int i = 0; i < 4; i++) {
        int kr = tr + 16 * i;
        float aT = aTs[kr];
        float4 o;
        o.x = aT * acc[i][0]; o.y = aT * acc[i][1];
        o.z = aT * acc[i][2]; o.w = aT * acc[i][3];
        *(float4*)&Q[((size_t)(bh * C_CH + c) * D_SZ + kr) * D_SZ + q4] = o;
    }
    if (tid < D_SZ)
        P[(size_t)(bh * C_CH + c) * D_SZ + tid] = aTs[tid];
}

__global__ __launch_bounds__(64) void phase2(const float* __restrict__ P,
                                             float* __restrict__ Qrw,
                                             float* __restrict__ out2) {
    int bh = blockIdx.x, kqi = blockIdx.y;
    int lane = threadIdx.x;
    float S[16];
    #pragma unroll
    for (int i = 0; i < 16; i++) S[i] = 0.f;

    size_t pb = (size_t)bh * C_CH * D_SZ + kqi * 16;
    size_t qb = ((size_t)bh * C_CH * D_SZ + kqi * 16) * D_SZ + lane;
    const size_t qstep = (size_t)D_SZ * D_SZ;

    float pc[16], qc[16];
    #pragma unroll
    for (int i = 0; i < 16; i++) {
        pc[i] = P[pb + i];
        qc[i] = Qrw[qb + (size_t)i * D_SZ];
    }
    for (int c = 0; c < C_CH; c++) {
        float pn[16] = {}, qn[16] = {};
        if (c < C_CH - 1) {
            #pragma unroll
            for (int i = 0; i < 16; i++) {
                pn[i] = P[pb + (size_t)(c + 1) * D_SZ + i];
                qn[i] = Qrw[qb + (size_t)(c + 1) * qstep + (size_t)i * D_SZ];
            }
        }
        #pragma unroll
        for (int i = 0; i < 16; i++) {
            Qrw[qb + (size_t)c * qstep + (size_t)i * D_SZ] = S[i];
            S[i] = fmaf(pc[i], S[i], qc[i]);
            pc[i] = pn[i]; qc[i] = qn[i];
        }
    }
    size_t ob = ((size_t)bh * D_SZ + kqi * 16) * D_SZ + lane;
    #pragma unroll
    for (int i = 0; i < 16; i++) out2[ob + (size_t)i * D_SZ] = S[i];
}

__global__ __launch_bounds__(256, 4) void phase3_mfma(
    const float* __restrict__ kq, const float* __restrict__ vq,
    const float* __restrict__ dq, const float* __restrict__ rq,
    const float* __restrict__ gq, const float* __restrict__ Bs,
    const float* __restrict__ bd, const float* __restrict__ tf,
    const float* __restrict__ Sstart, float* __restrict__ out)
{
    int c = blockIdx.x, bh = blockIdx.y;
    int b = bh >> 4, h = bh & 15;
    int tid = threadIdx.x;
    alignas(16) __shared__ ushort tQ[4096];   // q~ [t][k]
    alignas(16) __shared__ ushort tKG[4096];  // k~ [tau][k] -> G [t][tau]
    alignas(16) __shared__ ushort tS0[4096];  // S0^T [v][k]
    alignas(16) __shared__ ushort tVT[4096];  // V^T [v][tau]
    __shared__ float part[4][D_SZ];

    int t0 = c * T_CH;
    size_t base = ((size_t)(b * L_SZ + t0) * H_SZ + h) * D_SZ;
    size_t sb = (size_t)(bh * C_CH + c) * D_SZ * D_SZ;

    int tr = tid >> 4;           // 0..15
    int v4 = (tid & 15) * 4;

    // stage V^T and S0^T as bf16 (u16 scatter)
    #pragma unroll
    for (int i = 0; i < 4; i++) {
        int t = tr + 16 * i;     // row of V (tau) / row of S0 (k)
        float4 vv = *(const float4*)&vq[base + (size_t)t * STRIDE_T + v4];
        float4 s0 = *(const float4*)&Sstart[sb + (size_t)t * D_SZ + v4];
        tVT[SWZ(v4 + 0, t)] = f2bf(vv.x);
        tVT[SWZ(v4 + 1, t)] = f2bf(vv.y);
        tVT[SWZ(v4 + 2, t)] = f2bf(vv.z);
        tVT[SWZ(v4 + 3, t)] = f2bf(vv.w);
        tS0[SWZ(v4 + 0, t)] = f2bf(s0.x);
        tS0[SWZ(v4 + 1, t)] = f2bf(s0.y);
        tS0[SWZ(v4 + 2, t)] = f2bf(s0.z);
        tS0[SWZ(v4 + 3, t)] = f2bf(s0.w);
    }

    // per-column cumsum pass -> q~, k~ (bf16)
    int kcol = tid & 63, qq = tid >> 6;
    float dts[16], kin[16], bsv[16];
    #pragma unroll
    for (int j = 0; j < 16; j++) {
        int t = qq * 16 + j;
        dts[j] = dq[base + (size_t)t * STRIDE_T + kcol];
        kin[j] = kq[base + (size_t)t * STRIDE_T + kcol];
        bsv[j] = Bs[b * L_SZ + t0 + t];
    }
    float psum = 0.f;
    #pragma unroll
    for (int j = 0; j < 16; j++) psum += dts[j];
    part[qq][kcol] = psum;
    __syncthreads();                                   // B1

    float cs = 0.f;
    {
        float p0 = part[0][kcol], p1 = part[1][kcol], p2 = part[2][kcol];
        if (qq > 0) cs += p0;
        if (qq > 1) cs += p1;
        if (qq > 2) cs += p2;
    }
    float bdk = bd[h * D_SZ + kcol];
    #pragma unroll
    for (int j = 0; j < 16; j++) {
        int t = qq * 16 + j;
        cs += dts[j];
        tQ[SWZ(t, kcol)]  = f2bf(kin[j] * __expf(-bdk * cs));
        tKG[SWZ(t, kcol)] = f2bf(bsv[j] * kin[j] * __expf(bdk * cs));
    }
    __syncthreads();                                   // B2

    int lane = tid & 63, w = tid >> 6;   // wave w owns t-band 16w..16w+15
    int lg = lane >> 4, lr = lane & 15;

    f32x4 gacc[4] = {};
    f32x4 acc[4] = {};

    // G = q~ . k~^T   and   O1 = q~ . S0  (B-frag == contiguous read of Y[row][k])
    #pragma unroll
    for (int s = 0; s < 2; s++) {
        short8 a = *(const short8*)&tQ[SWZ(16 * w + lr, 32 * s + lg * 8)];
        #pragma unroll
        for (int j = 0; j < 4; j++) {
            short8 bk = *(const short8*)&tKG[SWZ(16 * j + lr, 32 * s + lg * 8)];
            gacc[j] = __builtin_amdgcn_mfma_f32_16x16x32_bf16(a, bk, gacc[j], 0, 0, 0);
            short8 bs8 = *(const short8*)&tS0[SWZ(16 * j + lr, 32 * s + lg * 8)];
            acc[j] = __builtin_amdgcn_mfma_f32_16x16x32_bf16(a, bs8, acc[j], 0, 0, 0);
        }
    }
    __syncthreads();                                   // B3: k~ readers done

    // masked G -> tKG (C-frag: t = 16w + lg*4 + reg, tau = 16j + lr)
    #pragma unroll
    for (int j = 0; j < 4; j++) {
        #pragma unroll
        for (int reg = 0; reg < 4; reg++) {
            int t = 16 * w + lg * 4 + reg;
            int tau = 16 * j + lr;
            tKG[SWZ(t, tau)] = (tau <= t) ? f2bf(gacc[j][reg]) : (ushort)0;
        }
    }
    __syncthreads();                                   // B4

    // O2 += G . V
    #pragma unroll
    for (int s = 0; s < 2; s++) {
        short8 a = *(const short8*)&tKG[SWZ(16 * w + lr, 32 * s + lg * 8)];
        #pragma unroll
        for (int j = 0; j < 4; j++) {
            short8 bv = *(const short8*)&tVT[SWZ(16 * j + lr, 32 * s + lg * 8)];
            acc[j] = __builtin_amdgcn_mfma_f32_16x16x32_bf16(a, bv, acc[j], 0, 0, 0);
        }
    }

    // epilogue: out = r * (acc + tf*k*v) * g    (fp32 from global; k,v L2-hot)
    #pragma unroll
    for (int j = 0; j < 4; j++) {
        int v = 16 * j + lr;
        float tfv = tf[h * D_SZ + v];
        #pragma unroll
        for (int reg = 0; reg < 4; reg++) {
            int t = 16 * w + lg * 4 + reg;
            size_t off = base + (size_t)t * STRIDE_T + v;
            float kk = kq[off];
            float vv = vq[off];
            float rr = rq[off];
            float gg = gq[off];
            out[off] = rr * (acc[j][reg] + tfv * kk * vv) * gg;
        }
    }
}

extern "C" void kernel_launch(void* const* d_in, const int* in_sizes, int n_in,
                              void* d_out, int out_size, void* d_ws, size_t ws_size,
                              hipStream_t stream) {
    const float* k    = (const float*)d_in[0];
    const float* v    = (const float*)d_in[1];
    const float* dt   = (const float*)d_in[2];
    const float* Bvec = (const float*)d_in[3];
    // d_in[4] = C_vec (unused by reference)
    const float* r    = (const float*)d_in[5];
    const float* g    = (const float*)d_in[6];
    const float* bd   = (const float*)d_in[7];
    const float* tf   = (const float*)d_in[8];

    float* out  = (float*)d_out;
    float* out2 = out + (size_t)B_SZ * L_SZ * H_SZ * D_SZ;

    float* Bs = (float*)d_ws;
    float* P  = Bs + B_SZ * L_SZ;
    float* Q  = P + (size_t)BH * C_CH * D_SZ;

    bs_kernel<<<dim3(B_SZ * L_SZ / 4), 256, 0, stream>>>(Bvec, Bs);
    phase1_mm<<<dim3(C_CH, BH), 256, 0, stream>>>(k, v, dt, Bs, bd, P, Q);
    phase2<<<dim3(BH, 4), 64, 0, stream>>>(P, Q, out2);
    phase3_mfma<<<dim3(C_CH, BH), 256, 0, stream>>>(k, v, dt, r, g, Bs, bd, tf, Q, out);
}

// Round 6
// 82.130 us; speedup vs baseline: 2.7378x; 1.2065x over previous
//
#include <hip/hip_runtime.h>

// ParallelHybridScan: chunked linear scan as per-chunk MFMA matmuls.
// B=4 L=2048 H=16 D=64. Chunk T=64 -> C=32. BH=64.
// q~[t,k]=k*exp(-bd*cs[t,k]); k~[t,k]=Bs_t*k*exp(+bd*cs[t,k]); aT=exp(-bd*cs[63,k])
// Phase1 (MFMA): Q_c = diag(aT)*(K~^T V) [bf16]; P_c = aT [fp32]
// Phase2: S_{c+1} = P_c*S_c + Q_c (fp32 state, bf16 I/O; overwrites Q with start states)
// Phase3 (MFMA): G = masked(q~ k~^T); O = G V + q~ S0; out = r*(O+tf*k*v)*g
//
// R6 vs R5: conflict-free transposed staging via column-pass (thread owns an
// output ROW, two short8 stores) — R5's u16 scatter was ~16-way conflicted
// (3.67M cycles). phase1 moved to MFMA. Q workspace bf16. phase3 epilogue:
// acc -> fp32 LDS tile (aliases dead tQ+tKG, 2-way-free swizzle) -> coalesced
// column-pass using kin/vin still in registers (only r,g re-read).

#define B_SZ 4
#define L_SZ 2048
#define H_SZ 16
#define D_SZ 64
#define T_CH 64
#define C_CH (L_SZ / T_CH)   // 32
#define BH (B_SZ * H_SZ)     // 64
#define STRIDE_T (H_SZ * D_SZ)

typedef short short8 __attribute__((ext_vector_type(8)));
typedef float f32x4 __attribute__((ext_vector_type(4)));

// bf16 tile ushort[64][64]; 16B-block XOR swizzle; verified conflict-free for
// short8 row reads (A/B frags) and 2-way-free for scalar column writes.
#define SWZ(row, col) (((row) << 6) + ((col) ^ (((row) & 7) << 3)))

__device__ __forceinline__ ushort f2bf(float x) {
    unsigned u = __float_as_uint(x);
    u += 0x7FFFu + ((u >> 16) & 1u);   // round-to-nearest-even
    return (ushort)(u >> 16);
}
__device__ __forceinline__ float bf2f(ushort x) {
    return __uint_as_float(((unsigned)x) << 16);
}

__global__ __launch_bounds__(256) void bs_kernel(const float* __restrict__ Bvec,
                                                 float* __restrict__ Bs) {
    int wid = (blockIdx.x * 256 + threadIdx.x) >> 6;
    int lane = threadIdx.x & 63;
    if (wid >= B_SZ * L_SZ) return;
    float s = Bvec[wid * D_SZ + lane];
    #pragma unroll
    for (int m = 32; m >= 1; m >>= 1) s += __shfl_xor(s, m, 64);
    if (lane == 0) Bs[wid] = s * (1.0f / 64.0f);
}

__global__ __launch_bounds__(256, 4) void phase1_mfma(
    const float* __restrict__ kq, const float* __restrict__ vq,
    const float* __restrict__ dq, const float* __restrict__ Bs,
    const float* __restrict__ bd, float* __restrict__ P,
    ushort* __restrict__ Qbf)
{
    int c = blockIdx.x, bh = blockIdx.y;
    int b = bh >> 4, h = bh & 15;
    int tid = threadIdx.x;
    __shared__ __align__(16) ushort tKT[4096];  // K~^T [k][tau]
    __shared__ __align__(16) ushort tVT[4096];  // V^T  [v][tau]
    __shared__ float part[4][D_SZ];
    __shared__ float aTs[D_SZ];

    int t0 = c * T_CH;
    size_t base = ((size_t)(b * L_SZ + t0) * H_SZ + h) * D_SZ;
    int col = tid & 63, qq = tid >> 6;

    // column pass: thread owns column `col`, rows qq*16..qq*16+15
    float dts[16], kin[16], vin[16];
    #pragma unroll
    for (int j = 0; j < 16; j++) {
        size_t off = base + (size_t)(qq * 16 + j) * STRIDE_T + col;
        dts[j] = dq[off];
        kin[j] = kq[off];
        vin[j] = vq[off];
    }
    float psum = 0.f;
    #pragma unroll
    for (int j = 0; j < 16; j++) psum += dts[j];
    part[qq][col] = psum;
    __syncthreads();                                   // B1

    float cs = 0.f;
    {
        float p0 = part[0][col], p1 = part[1][col], p2 = part[2][col];
        if (qq > 0) cs += p0;
        if (qq > 1) cs += p1;
        if (qq > 2) cs += p2;
    }
    float bdk = bd[h * D_SZ + col];
    short8 klo, khi, vlo, vhi;
    #pragma unroll
    for (int j = 0; j < 16; j++) {
        int t = qq * 16 + j;
        cs += dts[j];
        float bs = Bs[b * L_SZ + t0 + t];
        ushort kt = f2bf(bs * kin[j] * __expf(bdk * cs));
        ushort vt = f2bf(vin[j]);
        if (j < 8) { klo[j] = (short)kt; vlo[j] = (short)vt; }
        else       { khi[j - 8] = (short)kt; vhi[j - 8] = (short)vt; }
    }
    if (qq == 3) aTs[col] = __expf(-bdk * cs);
    *(short8*)&tKT[SWZ(col, qq * 16)]     = klo;
    *(short8*)&tKT[SWZ(col, qq * 16 + 8)] = khi;
    *(short8*)&tVT[SWZ(col, qq * 16)]     = vlo;
    *(short8*)&tVT[SWZ(col, qq * 16 + 8)] = vhi;
    __syncthreads();                                   // B2

    // C[k][v] = sum_tau K~^T[k][tau] * V^T[v][tau]
    int lane = tid & 63, w = tid >> 6;
    int lg = lane >> 4, lr = lane & 15;
    f32x4 acc[4] = {};
    #pragma unroll
    for (int s = 0; s < 2; s++) {
        short8 a = *(const short8*)&tKT[SWZ(16 * w + lr, 32 * s + lg * 8)];
        #pragma unroll
        for (int j = 0; j < 4; j++) {
            short8 bv = *(const short8*)&tVT[SWZ(16 * j + lr, 32 * s + lg * 8)];
            acc[j] = __builtin_amdgcn_mfma_f32_16x16x32_bf16(a, bv, acc[j], 0, 0, 0);
        }
    }

    size_t qb = (size_t)(bh * C_CH + c) * (D_SZ * D_SZ);
    #pragma unroll
    for (int j = 0; j < 4; j++) {
        #pragma unroll
        for (int reg = 0; reg < 4; reg++) {
            int k = 16 * w + lg * 4 + reg;
            Qbf[qb + k * D_SZ + 16 * j + lr] = f2bf(aTs[k] * acc[j][reg]);
        }
    }
    if (tid < D_SZ)
        P[(size_t)(bh * C_CH + c) * D_SZ + tid] = aTs[tid];
}

// Sequential combine; fp32 state in regs, bf16 Q I/O, fp32 out2.
__global__ __launch_bounds__(64) void phase2(const float* __restrict__ P,
                                             ushort* __restrict__ Qrw,
                                             float* __restrict__ out2) {
    int bh = blockIdx.x, kqi = blockIdx.y;
    int lane = threadIdx.x;
    float S[16];
    #pragma unroll
    for (int i = 0; i < 16; i++) S[i] = 0.f;

    size_t pb = (size_t)bh * C_CH * D_SZ + kqi * 16;
    size_t qb = ((size_t)bh * C_CH * D_SZ + kqi * 16) * D_SZ + lane;
    const size_t qstep = (size_t)D_SZ * D_SZ;

    float pc[16]; ushort qc[16];
    #pragma unroll
    for (int i = 0; i < 16; i++) {
        pc[i] = P[pb + i];
        qc[i] = Qrw[qb + (size_t)i * D_SZ];
    }
    for (int c = 0; c < C_CH; c++) {
        float pn[16] = {}; ushort qn[16] = {};
        if (c < C_CH - 1) {
            #pragma unroll
            for (int i = 0; i < 16; i++) {
                pn[i] = P[pb + (size_t)(c + 1) * D_SZ + i];
                qn[i] = Qrw[qb + (size_t)(c + 1) * qstep + (size_t)i * D_SZ];
            }
        }
        #pragma unroll
        for (int i = 0; i < 16; i++) {
            Qrw[qb + (size_t)c * qstep + (size_t)i * D_SZ] = f2bf(S[i]);
            S[i] = fmaf(pc[i], S[i], bf2f(qc[i]));
            pc[i] = pn[i]; qc[i] = qn[i];
        }
    }
    size_t ob = ((size_t)bh * D_SZ + kqi * 16) * D_SZ + lane;
    #pragma unroll
    for (int i = 0; i < 16; i++) out2[ob + (size_t)i * D_SZ] = S[i];
}

__global__ __launch_bounds__(256, 4) void phase3_mfma(
    const float* __restrict__ kq, const float* __restrict__ vq,
    const float* __restrict__ dq, const float* __restrict__ rq,
    const float* __restrict__ gq, const float* __restrict__ Bs,
    const float* __restrict__ bd, const float* __restrict__ tf,
    const ushort* __restrict__ Sb, float* __restrict__ out)
{
    int c = blockIdx.x, bh = blockIdx.y;
    int b = bh >> 4, h = bh & 15;
    int tid = threadIdx.x;
    __shared__ __align__(16) ushort SH[16384];          // 32 KB
    ushort* tQ  = SH;                                   // q~ [t][k]
    ushort* tKG = SH + 4096;                            // k~ [tau][k] -> G [t][tau]
    ushort* tS0 = SH + 8192;                            // S0^T [v][k]
    ushort* tVT = SH + 12288;                           // V^T [v][tau]
    float*  ACC = (float*)SH;                           // fp32 [64][64] (aliases tQ+tKG, used after all tiles dead)
    __shared__ float part[4][D_SZ];

    int t0 = c * T_CH;
    size_t base = ((size_t)(b * L_SZ + t0) * H_SZ + h) * D_SZ;
    size_t sb = (size_t)(bh * C_CH + c) * (D_SZ * D_SZ);
    int col = tid & 63, qq = tid >> 6;

    // column pass: loads for cumsum + transposed staging
    float dts[16], kin[16], vin[16];
    ushort s0c[16];
    #pragma unroll
    for (int j = 0; j < 16; j++) {
        int t = qq * 16 + j;
        size_t off = base + (size_t)t * STRIDE_T + col;
        dts[j] = dq[off];
        kin[j] = kq[off];
        vin[j] = vq[off];
        s0c[j] = Sb[sb + (size_t)t * D_SZ + col];   // S0[k=t][v=col]
    }
    float psum = 0.f;
    #pragma unroll
    for (int j = 0; j < 16; j++) psum += dts[j];
    part[qq][col] = psum;
    __syncthreads();                                   // B1

    float cs = 0.f;
    {
        float p0 = part[0][col], p1 = part[1][col], p2 = part[2][col];
        if (qq > 0) cs += p0;
        if (qq > 1) cs += p1;
        if (qq > 2) cs += p2;
    }
    float bdk = bd[h * D_SZ + col];
    short8 vlo, vhi, slo, shi;
    #pragma unroll
    for (int j = 0; j < 16; j++) {
        int t = qq * 16 + j;
        cs += dts[j];
        float bs = Bs[b * L_SZ + t0 + t];
        tQ[SWZ(t, col)]  = f2bf(kin[j] * __expf(-bdk * cs));   // row-write, 2-way free
        tKG[SWZ(t, col)] = f2bf(bs * kin[j] * __expf(bdk * cs));
        ushort vt = f2bf(vin[j]);
        if (j < 8) { vlo[j] = (short)vt; slo[j] = (short)s0c[j]; }
        else       { vhi[j - 8] = (short)vt; shi[j - 8] = (short)s0c[j]; }
    }
    *(short8*)&tVT[SWZ(col, qq * 16)]     = vlo;       // V^T row `col`
    *(short8*)&tVT[SWZ(col, qq * 16 + 8)] = vhi;
    *(short8*)&tS0[SWZ(col, qq * 16)]     = slo;       // S0^T row `col`
    *(short8*)&tS0[SWZ(col, qq * 16 + 8)] = shi;
    __syncthreads();                                   // B2

    int lane = tid & 63, w = tid >> 6;
    int lg = lane >> 4, lr = lane & 15;

    // G = q~ k~^T ; O1 = q~ S0
    f32x4 gacc[4] = {};
    f32x4 acc[4] = {};
    #pragma unroll
    for (int s = 0; s < 2; s++) {
        short8 a = *(const short8*)&tQ[SWZ(16 * w + lr, 32 * s + lg * 8)];
        #pragma unroll
        for (int j = 0; j < 4; j++) {
            short8 bk = *(const short8*)&tKG[SWZ(16 * j + lr, 32 * s + lg * 8)];
            gacc[j] = __builtin_amdgcn_mfma_f32_16x16x32_bf16(a, bk, gacc[j], 0, 0, 0);
            short8 b0 = *(const short8*)&tS0[SWZ(16 * j + lr, 32 * s + lg * 8)];
            acc[j] = __builtin_amdgcn_mfma_f32_16x16x32_bf16(a, b0, acc[j], 0, 0, 0);
        }
    }
    __syncthreads();                                   // B3: k~ readers done

    // masked G -> tKG  (C-frag: t = 16w + lg*4 + reg, tau = 16j + lr)
    #pragma unroll
    for (int j = 0; j < 4; j++) {
        #pragma unroll
        for (int reg = 0; reg < 4; reg++) {
            int t = 16 * w + lg * 4 + reg;
            int tau = 16 * j + lr;
            tKG[SWZ(t, tau)] = (tau <= t) ? f2bf(gacc[j][reg]) : (ushort)0;
        }
    }
    __syncthreads();                                   // B4

    // O2 += G V
    #pragma unroll
    for (int s = 0; s < 2; s++) {
        short8 a = *(const short8*)&tKG[SWZ(16 * w + lr, 32 * s + lg * 8)];
        #pragma unroll
        for (int j = 0; j < 4; j++) {
            short8 bv = *(const short8*)&tVT[SWZ(16 * j + lr, 32 * s + lg * 8)];
            acc[j] = __builtin_amdgcn_mfma_f32_16x16x32_bf16(a, bv, acc[j], 0, 0, 0);
        }
    }
    __syncthreads();                                   // B5: all bf16 tiles dead

    // acc -> fp32 LDS tile, 2-way-free swizzle: col ^ (((t>>2)&1)<<4)
    #pragma unroll
    for (int j = 0; j < 4; j++) {
        #pragma unroll
        for (int reg = 0; reg < 4; reg++) {
            int t = 16 * w + lg * 4 + reg;
            int v = 16 * j + lr;
            ACC[t * D_SZ + (v ^ (((t >> 2) & 1) << 4))] = acc[j][reg];
        }
    }
    __syncthreads();                                   // B6

    // coalesced column-pass epilogue; kin/vin still live in registers
    float tfv = tf[h * D_SZ + col];
    #pragma unroll
    for (int j = 0; j < 16; j++) {
        int t = qq * 16 + j;
        size_t off = base + (size_t)t * STRIDE_T + col;
        float a = ACC[t * D_SZ + (col ^ (((t >> 2) & 1) << 4))];
        out[off] = rq[off] * (a + tfv * kin[j] * vin[j]) * gq[off];
    }
}

extern "C" void kernel_launch(void* const* d_in, const int* in_sizes, int n_in,
                              void* d_out, int out_size, void* d_ws, size_t ws_size,
                              hipStream_t stream) {
    const float* k    = (const float*)d_in[0];
    const float* v    = (const float*)d_in[1];
    const float* dt   = (const float*)d_in[2];
    const float* Bvec = (const float*)d_in[3];
    // d_in[4] = C_vec (unused by reference)
    const float* r    = (const float*)d_in[5];
    const float* g    = (const float*)d_in[6];
    const float* bd   = (const float*)d_in[7];
    const float* tf   = (const float*)d_in[8];

    float* out  = (float*)d_out;
    float* out2 = out + (size_t)B_SZ * L_SZ * H_SZ * D_SZ;

    float* Bs  = (float*)d_ws;                        // B*L fp32
    float* P   = Bs + B_SZ * L_SZ;                    // BH*C*D fp32
    ushort* Qb = (ushort*)(P + (size_t)BH * C_CH * D_SZ);  // BH*C*D*D bf16 (16.8 MB)

    bs_kernel<<<dim3(B_SZ * L_SZ / 4), 256, 0, stream>>>(Bvec, Bs);
    phase1_mfma<<<dim3(C_CH, BH), 256, 0, stream>>>(k, v, dt, Bs, bd, P, Qb);
    phase2<<<dim3(BH, 4), 64, 0, stream>>>(P, Qb, out2);
    phase3_mfma<<<dim3(C_CH, BH), 256, 0, stream>>>(k, v, dt, r, g, Bs, bd, tf, Qb, out);
}